// Round 1
// baseline (3525.949 us; speedup 1.0000x reference)
//
#include <hip/hip_runtime.h>
#include <math.h>

// ---------------- problem constants ----------------
#define B_ 8192
#define T_ 223
#define D_ 7
#define H_ 128
#define G_ 512      // 4*H
#define E_ 50
#define O_ 29
#define A_ 9
#define TD_ (T_*D_)     // 1561
#define NB 16           // batch rows per block (main kernel)  [was 32 -> 2 blocks/CU]
#define NTHR 512
#define MB 8            // batch rows per block (head kernel)
#define MS_BG 128       // msum batch groups

// ---------------- workspace layout (float offsets) ----------------
#define WS_MINV  0                            // raw msum_t sums, T floats (main computes 1/(s+1e-5))
#define WS_ACC   (WS_MINV + T_)               // [0]=x_loss raw sum, [1]=y_loss raw sum
#define WS_WCATT (WS_ACC + 2)                 // [178][128] transposed W_cat
#define WS_HFIN  (WS_WCATT + 178*H_)          // final h, [B][128] fp32

// ---------------- output layout (floats) ----------------
#define OUT_YH  3
#define OUT_IMP (OUT_YH + B_*O_)              // 237571
#define OUT_LAB (OUT_IMP + B_*T_*D_)          // 13025283

typedef __attribute__((ext_vector_type(8))) short short8;   // 8 bf16 = 4 VGPRs
typedef __attribute__((ext_vector_type(4))) float floatx4;
#define MFMA16(Av,Bv,Cv) __builtin_amdgcn_mfma_f32_16x16x32_bf16((Av),(Bv),(Cv),0,0,0)

__device__ __forceinline__ unsigned short f2bf(float f) {   // RNE fp32->bf16
    unsigned int u = __builtin_bit_cast(unsigned int, f);
    return (unsigned short)((u + 0x7FFFu + ((u >> 16) & 1u)) >> 16);
}
__device__ __forceinline__ float bf2f(unsigned short s) {
    unsigned int u = ((unsigned int)s) << 16;
    return __builtin_bit_cast(float, u);
}
__device__ __forceinline__ float rcp_(float x)  { return __builtin_amdgcn_rcpf(x); }
__device__ __forceinline__ float sigm(float x)  { return rcp_(1.f + __expf(-x)); }
__device__ __forceinline__ float tanh_(float x) { return 1.f - 2.f*rcp_(1.f + __expf(2.f*x)); }

// ================= prep: W_cat transpose + zero accumulators =================
__global__ void rits_prep(const float* __restrict__ W_cat, float* __restrict__ ws)
{
    int idx = blockIdx.x * 256 + threadIdx.x;
    if (idx < H_*178) {                      // W_cat [128][178] -> [178][128]
        int j = idx / 178, k = idx - j*178;
        ws[WS_WCATT + k*H_ + j] = W_cat[idx];
    }
    if (idx < T_) ws[WS_MINV + idx] = 0.f;
    if (idx < 2) ws[WS_ACC + idx] = 0.f;
}

// ================= per-step mask sums (coalesced, atomic partials) =================
// grid = 7 t-chunks x MS_BG batch groups; block 256 threads.
// Each block reads, for B_/MS_BG batch rows, a contiguous 32-timestep slice
// (224 floats, 896B) -> fully coalesced.  32 atomicAdd partials per block.
__global__ void rits_msum(const float* __restrict__ masks, float* __restrict__ ws)
{
    const int tc = blockIdx.x % 7;           // t-chunk of 32 steps
    const int bg = blockIdx.x / 7;           // batch group
    const int t0 = tc * 32;
    const int nt = (t0 + 32 <= T_) ? 32 : (T_ - t0);
    const int ncol = nt * D_;                // 224 or 217
    const int tid = threadIdx.x;
    __shared__ float sums[224];
    float s = 0.f;
    if (tid < ncol) {
        const int bpg = B_ / MS_BG;          // 64
        const float* p = masks + (size_t)bg * bpg * TD_ + (size_t)t0 * D_ + tid;
        #pragma unroll 4
        for (int b = 0; b < bpg; ++b) s += p[(size_t)b * TD_];
    }
    if (tid < 224) sums[tid] = (tid < ncol) ? s : 0.f;
    __syncthreads();
    if (tid < 32) {
        float r = 0.f;
        #pragma unroll
        for (int q = 0; q < 7; ++q) r += sums[tid*7 + q];
        if (t0 + tid < T_) atomicAdd(&ws[WS_MINV + t0 + tid], r);
    }
}

// ================= main scan kernel (MFMA) =================
// Formulation: D[gate j][batch b] = sum_k W_ext[j][k] * hext[b][k]
//   A-frags (W) persistent in VGPRs; B-frags (h / c_c,m ext) from LDS hbuf.
// Wave w owns gate M-tiles {w, 8+w, 16+w, 24+w} (one per i/f/g/o quadrant) so
// each lane's C rows give i,f,g,o for the SAME hidden j = w*16+quad*4+r.
// NB=16: single 16-row batch tile; grid 512 -> 2 blocks/CU for phase overlap.
__global__ __launch_bounds__(NTHR, 4) void rits_main(
    const float* __restrict__ values, const float* __restrict__ masks, const float* __restrict__ deltas,
    const float* __restrict__ W_td_h, const float* __restrict__ b_td_h,
    const float* __restrict__ W_td_x, const float* __restrict__ b_td_x,
    const float* __restrict__ W_hist, const float* __restrict__ b_hist,
    const float* __restrict__ W_feat, const float* __restrict__ b_feat,
    const float* __restrict__ W_comb, const float* __restrict__ b_comb,
    const float* __restrict__ W_ih, const float* __restrict__ W_hh,
    const float* __restrict__ b_ih, const float* __restrict__ b_hh,
    float* __restrict__ ws, float* __restrict__ out)
{
    // B-operand buffer: rows=batch(16), cols bf16: 0..127=h, 128..134=c_c,
    // 135..141=m, 142..159=0. Row stride 168 bf16 = 336B (16B-aligned, 2-way banks)
    __shared__ __attribute__((aligned(16))) unsigned short hbuf[NB*168];
    __shared__ __attribute__((aligned(16))) unsigned short dbuf[NB*72];   // d(t+1) bf16, cols 7..31 = 0
    __shared__ __attribute__((aligned(16))) unsigned short whis_lds[16*136]; // W_hist bf16, rows 7..15 = 0
    __shared__ float xs[NB*8], msh[NB*8], dsl[NB*8];
    __shared__ float xh_l[NB*8], xc_l[NB*8], gx_l[NB*8];
    __shared__ float bhist_l[8], tdx_l[8], btdx_l[8];
    __shared__ float impbuf[NB*16*7];       // 16-step imputation buffer (fp32)
    __shared__ float red[8];

    const int tid  = threadIdx.x;
    const int b0   = blockIdx.x * NB;
    const int lane = tid & 63;
    const int w    = tid >> 6;      // wave 0..7
    const int quad = lane >> 4;
    const int l15  = lane & 15;

    // ---- one-time LDS init ----
    for (int i = tid; i < NB*168; i += NTHR) hbuf[i] = 0;
    for (int i = tid; i < NB*72;  i += NTHR) dbuf[i] = 0;
    for (int i = tid; i < 16*136; i += NTHR) {
        int r = i / 136, c = i - r*136;
        whis_lds[i] = (r < 7 && c < 128) ? f2bf(W_hist[r*H_ + c]) : 0;
    }
    if (tid < 8) {
        bhist_l[tid] = (tid < 7) ? b_hist[tid] : 0.f;
        tdx_l[tid]   = (tid < 7) ? W_td_x[tid*D_ + tid] : 0.f;
        btdx_l[tid]  = (tid < 7) ? b_td_x[tid] : 0.f;
    }

    // ---- persistent weight fragments (per lane) ----
    short8 whhf[4][4];   // [gate c][kstep]  A[j=l15 of tile][k=quad*8+e]
    short8 winf[4];      // input kstep (k_ext 0..13 = W_ih, rest 0)
    short8 wtdf;         // W_td_h frag for gamma_h MFMA (j = w*16+l15, k<7)
    float  biasg_r[4][4];
    float  btdh_r[4];
    {
        union UU { short8 v; unsigned short u[8]; } fr;
        #pragma unroll
        for (int c = 0; c < 4; ++c) {
            const int j = (c*8 + w)*16 + l15;
            #pragma unroll
            for (int s = 0; s < 4; ++s) {
                const float* p = W_hh + j*H_ + s*32 + quad*8;
                #pragma unroll
                for (int e = 0; e < 8; ++e) fr.u[e] = f2bf(p[e]);
                whhf[c][s] = fr.v;
            }
            #pragma unroll
            for (int e = 0; e < 8; ++e) {
                int k = quad*8 + e;
                fr.u[e] = (k < 14) ? f2bf(W_ih[j*14 + k]) : (unsigned short)0;
            }
            winf[c] = fr.v;
            #pragma unroll
            for (int r = 0; r < 4; ++r) {
                int jj = (c*8 + w)*16 + quad*4 + r;
                biasg_r[c][r] = b_ih[jj] + b_hh[jj];
            }
        }
        #pragma unroll
        for (int e = 0; e < 8; ++e) {
            int k = quad*8 + e;
            fr.u[e] = (k < 7) ? f2bf(W_td_h[(w*16 + l15)*D_ + k]) : (unsigned short)0;
        }
        wtdf = fr.v;
        #pragma unroll
        for (int r = 0; r < 4; ++r) btdh_r[r] = b_td_h[w*16 + quad*4 + r];
    }

    // ---- A3 per-thread state ----
    const bool ldr = (tid < NB*D_);
    const int  lb  = tid / D_, li = tid - (tid/D_)*D_;
    float wfr[7], wcr[14], bfr = 0.f, bcr = 0.f;
    if (ldr) {
        #pragma unroll
        for (int k = 0; k < 7; ++k)  wfr[k] = (k == li) ? 0.f : W_feat[li*D_ + k];
        #pragma unroll
        for (int k = 0; k < 14; ++k) wcr[k] = W_comb[li*14 + k];
        bfr = b_feat[li];  bcr = b_comb[li];
    }

    float c_st[4] = {0,0,0,0};
    float lacc = 0.f;

    // input prefetch (regs hold step-t data at loop top)
    const long gbase = (long)(b0 + lb)*TD_ + li;
    float rx = 0.f, rm = 0.f, rd = 0.f;
    if (ldr) { rx = values[gbase]; rm = masks[gbase]; rd = deltas[gbase]; }

    const float* msums = ws + WS_MINV;

    for (int t = 0; t < T_; ++t) {
        if (ldr) { xs[lb*8+li] = rx; msh[lb*8+li] = rm; dsl[lb*8+li] = rd; }
        __syncthreads();                       // [S] stage + prev h-writes visible
        if (ldr && t + 1 < T_) {
            const long g = gbase + (long)(t+1)*D_;
            rx = values[g]; rm = masks[g]; rd = deltas[g];
        }

        // ---- B1: gate h-part (+ x_h on wave 7). h in hbuf is ALREADY decayed ----
        floatx4 acc[4];
        #pragma unroll
        for (int c = 0; c < 4; ++c) {
            floatx4 a = { biasg_r[c][0], biasg_r[c][1], biasg_r[c][2], biasg_r[c][3] };
            acc[c] = a;
        }
        floatx4 xh0 = {0,0,0,0};
        #pragma unroll
        for (int s = 0; s < 4; ++s) {
            short8 hb0 = *(const short8*)&hbuf[l15*168 + s*32 + quad*8];
            #pragma unroll
            for (int c = 0; c < 4; ++c)
                acc[c] = MFMA16(whhf[c][s], hb0, acc[c]);
            if (w == 7) {
                short8 wh = *(const short8*)&whis_lds[l15*136 + s*32 + quad*8];
                xh0 = MFMA16(wh, hb0, xh0);
            }
        }
        // wave 7: finish x_h, compute x_c / gamma_x, publish to LDS
        if (w == 7 && quad < 2) {
            const int b = l15;
            #pragma unroll
            for (int r = 0; r < 4; ++r) {
                const int i = quad*4 + r;
                if (i < 7) {
                    float xhv = xh0[r] + bhist_l[i];
                    float x = xs[b*8+i], m = msh[b*8+i], d = dsl[b*8+i];
                    xh_l[b*8+i] = xhv;
                    xc_l[b*8+i] = m*x + (1.f-m)*xhv;
                    gx_l[b*8+i] = __expf(-fmaxf(fmaf(d, tdx_l[i], btdx_l[i]), 0.f));
                }
            }
        }
        __syncthreads();                       // [B] x_h / x_c / gamma_x ready

        // ---- A3: z_h, alpha, c_h, c_c, imputation, loss; write ext cols + dbuf ----
        if (ldr) {
            const int b = lb, i = li;
            const float invt = 1.0f / (msums[t] + 1e-5f);
            const float x = xs[b*8+i], m = msh[b*8+i];
            float zh = bfr;
            #pragma unroll
            for (int k = 0; k < 7; ++k) zh = fmaf(wfr[k], xc_l[b*8+k], zh);
            float al = bcr;
            #pragma unroll
            for (int k = 0; k < 7; ++k) al = fmaf(wcr[k],   gx_l[b*8+k], al);
            #pragma unroll
            for (int k = 0; k < 7; ++k) al = fmaf(wcr[7+k], msh[b*8+k], al);
            const float xhv = xh_l[b*8+i];
            const float ch  = al*zh + (1.f-al)*xhv;
            const float cc  = m*x + (1.f-m)*ch;
            impbuf[(b*16 + (t & 15))*7 + i] = cc;
            hbuf[b*168 + 128 + i] = f2bf(cc);
            hbuf[b*168 + 135 + i] = f2bf(m);
            dbuf[b*72 + i] = f2bf(rd);         // d(t+1) for fused decay
            lacc = fmaf((fabsf(x-xhv) + fabsf(x-zh) + fabsf(x-ch)) * m, invt, lacc);
        }
        __syncthreads();                       // [C] c_c/m ext + dbuf ready

        // ---- B2: input part ----
        {
            short8 ib0 = *(const short8*)&hbuf[l15*168 + 128 + quad*8];
            #pragma unroll
            for (int c = 0; c < 4; ++c)
                acc[c] = MFMA16(winf[c], ib0, acc[c]);
        }
        // ---- fused gamma_h(t+1) via MFMA on d(t+1) ----
        floatx4 g0 = {0,0,0,0};
        const bool dec = (t + 1 < T_);
        if (dec) {
            short8 df0 = *(const short8*)&dbuf[l15*72 + quad*8];
            floatx4 z = {0,0,0,0};
            g0 = MFMA16(wtdf, df0, z);
        }
        // ---- LSTM update; write h (pre-decayed for next step) ----
        {
            const int b = l15;
            #pragma unroll
            for (int r = 0; r < 4; ++r) {
                float ig = acc[0][r], fg = acc[1][r];
                float gv = acc[2][r], og = acc[3][r];
                float cn = sigm(fg)*c_st[r] + sigm(ig)*tanh_(gv);
                c_st[r] = cn;
                float hn = sigm(og)*tanh_(cn);
                if (dec) hn *= __expf(-fmaxf(g0[r] + btdh_r[r], 0.f));
                hbuf[b*168 + w*16 + quad*4 + r] = f2bf(hn);
            }
        }

        // ---- imputation flush (contiguous 28B runs, 16 steps at a time) ----
        if ((t & 15) == 15 || t == T_ - 1) {
            const int t0 = t & ~15;
            const int b  = tid >> 4, c16 = tid & 15;
            if (b < NB && t0 + c16 <= t) {
                float* gp = out + (size_t)OUT_IMP + (size_t)(b0+b)*TD_ + (size_t)(t0+c16)*D_;
                const float* lp = &impbuf[(b*16 + c16)*7];
                #pragma unroll
                for (int e = 0; e < 7; ++e) gp[e] = lp[e];
            }
        }
    }
    __syncthreads();

    // ---- x_loss partial reduction ----
    for (int off = 32; off > 0; off >>= 1) lacc += __shfl_down(lacc, off, 64);
    if ((tid & 63) == 0) red[tid >> 6] = lacc;
    __syncthreads();
    if (tid == 0) {
        float s = 0.f;
        #pragma unroll
        for (int q = 0; q < 8; ++q) s += red[q];
        atomicAdd(&ws[WS_ACC], s);
    }
    // ---- final h -> workspace (fp32) ----
    for (int i = tid; i < NB*H_; i += NTHR) {
        int b = i >> 7, j = i & 127;
        ws[WS_HFIN + (size_t)(b0+b)*H_ + j] = bf2f(hbuf[b*168 + j]);
    }
}

// ================= classification head =================
__global__ __launch_bounds__(128) void rits_head(
    const float* __restrict__ probs, const float* __restrict__ ancillary, const int* __restrict__ labels,
    const float* __restrict__ W_anc, const float* __restrict__ b_anc,
    const float* __restrict__ b_cat,
    const float* __restrict__ W_out, const float* __restrict__ b_out,
    float* __restrict__ ws, float* __restrict__ out)
{
    __shared__ float hb[MB*H_];
    __shared__ float ancl[MB*52];
    __shared__ float hc[MB*H_];
    __shared__ float lg[MB*32];
    __shared__ float smx[MB], sinv[MB], ysum[MB];
    __shared__ float sq[MB*32];
    const int tid = threadIdx.x;
    const int bb0 = blockIdx.x * MB;

    for (int i = tid; i < MB*H_; i += 128) hb[i] = ws[WS_HFIN + (size_t)bb0*H_ + i];
    for (int i = tid; i < MB*E_; i += 128) {
        int b = i / E_, e = i - b*E_;
        float s = b_anc[e];
        #pragma unroll
        for (int a = 0; a < A_; ++a) s = fmaf(ancillary[(bb0+b)*A_ + a], W_anc[e*A_ + a], s);
        ancl[b*52+e] = fmaxf(s, 0.f);
    }
    __syncthreads();
    {
        const int j = tid;
        float s[MB];
        #pragma unroll
        for (int b = 0; b < MB; ++b) s[b] = b_cat[j];
        const float* wc = ws + WS_WCATT;
        for (int k = 0; k < H_; ++k) {
            float wv = wc[k*H_ + j];
            #pragma unroll
            for (int b = 0; b < MB; ++b) s[b] = fmaf(hb[b*H_+k], wv, s[b]);
        }
        for (int k = 0; k < E_; ++k) {
            float wv = wc[(H_+k)*H_ + j];
            #pragma unroll
            for (int b = 0; b < MB; ++b) s[b] = fmaf(ancl[b*52+k], wv, s[b]);
        }
        #pragma unroll
        for (int b = 0; b < MB; ++b) hc[b*H_+j] = fmaxf(s[b], 0.f);
    }
    __syncthreads();
    for (int i = tid; i < MB*O_; i += 128) {
        int b = i / O_, o = i - b*O_;
        float s = b_out[o];
        for (int k = 0; k < H_; ++k) s = fmaf(hc[b*H_+k], W_out[o*H_+k], s);
        lg[b*32+o] = s;
    }
    __syncthreads();
    if (tid < MB) {
        float mx = -1e30f;
        for (int o = 0; o < O_; ++o) mx = fmaxf(mx, lg[tid*32+o]);
        float se = 0.f;
        for (int o = 0; o < O_; ++o) se += __expf(lg[tid*32+o] - mx);
        smx[tid] = mx; sinv[tid] = 1.f / se;
    }
    __syncthreads();
    for (int i = tid; i < MB*O_; i += 128) {
        int b = i / O_, o = i - b*O_;
        float y = __expf(lg[b*32+o] - smx[b]) * sinv[b];
        out[OUT_YH + (size_t)(bb0+b)*O_ + o] = y;
        float d = y - probs[(size_t)(bb0+b)*O_ + o];
        sq[b*32+o] = d*d;
    }
    __syncthreads();
    if (tid < MB) {
        float s = 0.f;
        for (int o = 0; o < O_; ++o) s += sq[tid*32+o];
        ysum[tid] = s;
        out[OUT_LAB + bb0 + tid] = (float)labels[bb0 + tid];
    }
    __syncthreads();
    if (tid == 0) {
        float s = 0.f;
        #pragma unroll
        for (int b = 0; b < MB; ++b) s += ysum[b];
        atomicAdd(&ws[WS_ACC+1], s);
    }
}

// ================= finalize scalars =================
__global__ void rits_fin(const float* __restrict__ ws, float* __restrict__ out)
{
    if (blockIdx.x == 0 && threadIdx.x == 0) {
        float xl = ws[WS_ACC] * 0.3f;
        float yl = ws[WS_ACC+1] * (1.0f / (8192.0f + 1e-5f));
        out[0] = xl; out[1] = yl; out[2] = xl + yl;
    }
}

extern "C" void kernel_launch(void* const* d_in, const int* in_sizes, int n_in,
                              void* d_out, int out_size, void* d_ws, size_t ws_size,
                              hipStream_t stream)
{
    const float* values = (const float*)d_in[0];
    const float* masks  = (const float*)d_in[1];
    const float* deltas = (const float*)d_in[2];
    const float* probs  = (const float*)d_in[3];
    const float* ancil  = (const float*)d_in[4];
    const int*   labels = (const int*)  d_in[5];
    const float* W_td_h = (const float*)d_in[6];
    const float* b_td_h = (const float*)d_in[7];
    const float* W_td_x = (const float*)d_in[8];
    const float* b_td_x = (const float*)d_in[9];
    const float* W_hist = (const float*)d_in[10];
    const float* b_hist = (const float*)d_in[11];
    const float* W_feat = (const float*)d_in[12];
    const float* b_feat = (const float*)d_in[13];
    const float* W_comb = (const float*)d_in[14];
    const float* b_comb = (const float*)d_in[15];
    const float* W_ih   = (const float*)d_in[16];
    const float* W_hh   = (const float*)d_in[17];
    const float* b_ih   = (const float*)d_in[18];
    const float* b_hh   = (const float*)d_in[19];
    const float* W_anc  = (const float*)d_in[20];
    const float* b_anc  = (const float*)d_in[21];
    const float* W_cat  = (const float*)d_in[22];
    const float* b_cat  = (const float*)d_in[23];
    const float* W_out  = (const float*)d_in[24];
    const float* b_out  = (const float*)d_in[25];
    float* ws  = (float*)d_ws;
    float* out = (float*)d_out;

    hipLaunchKernelGGL(rits_prep, dim3((H_*178 + 255)/256), dim3(256), 0, stream, W_cat, ws);
    hipLaunchKernelGGL(rits_msum, dim3(7*MS_BG), dim3(256), 0, stream, masks, ws);
    hipLaunchKernelGGL(rits_main, dim3(B_/NB), dim3(NTHR), 0, stream,
                       values, masks, deltas, W_td_h, b_td_h, W_td_x, b_td_x,
                       W_hist, b_hist, W_feat, b_feat, W_comb, b_comb,
                       W_ih, W_hh, b_ih, b_hh, ws, out);
    hipLaunchKernelGGL(rits_head, dim3(B_/MB), dim3(128), 0, stream,
                       probs, ancil, labels, W_anc, b_anc, b_cat, W_out, b_out, ws, out);
    hipLaunchKernelGGL(rits_fin, dim3(1), dim3(1), 0, stream, ws, out);
}

// Round 2
// 1737.919 us; speedup vs baseline: 2.0288x; 2.0288x over previous
//
#include <hip/hip_runtime.h>
#include <math.h>

// ---------------- problem constants ----------------
#define B_ 8192
#define T_ 223
#define D_ 7
#define H_ 128
#define E_ 50
#define O_ 29
#define A_ 9
#define TD_ (T_*D_)     // 1561
#define NB 16           // batch rows per block -> grid 512 = 2 blocks/CU
#define NTHR 512
#define MB 8            // batch rows per block (head kernel)
#define MS_BG 128       // msum batch groups

// ---------------- workspace layout (float offsets) ----------------
#define WS_MINV  0                            // raw msum_t sums, T floats
#define WS_ACC   (WS_MINV + T_)               // [0]=x_loss raw sum, [1]=y_loss raw sum
#define WS_WCATT (WS_ACC + 2)                 // [178][128] transposed W_cat
#define WS_HFIN  (WS_WCATT + 178*H_)          // final h, [B][128] fp32

// ---------------- output layout (floats) ----------------
#define OUT_YH  3
#define OUT_IMP (OUT_YH + B_*O_)              // 237571
#define OUT_LAB (OUT_IMP + B_*T_*D_)          // 13025283

typedef __attribute__((ext_vector_type(8))) short short8;   // 8 bf16 = 4 VGPRs
typedef __attribute__((ext_vector_type(4))) float floatx4;
#define MFMA16(Av,Bv,Cv) __builtin_amdgcn_mfma_f32_16x16x32_bf16((Av),(Bv),(Cv),0,0,0)

__device__ __forceinline__ unsigned short f2bf(float f) {   // RNE fp32->bf16
    unsigned int u = __builtin_bit_cast(unsigned int, f);
    return (unsigned short)((u + 0x7FFFu + ((u >> 16) & 1u)) >> 16);
}
__device__ __forceinline__ float bf2f(unsigned short s) {
    unsigned int u = ((unsigned int)s) << 16;
    return __builtin_bit_cast(float, u);
}
__device__ __forceinline__ float rcp_(float x)  { return __builtin_amdgcn_rcpf(x); }
__device__ __forceinline__ float sigm(float x)  { return rcp_(1.f + __expf(-x)); }
__device__ __forceinline__ float tanh_(float x) { return 1.f - 2.f*rcp_(1.f + __expf(2.f*x)); }
// force a wave-uniform float into an SGPR (register-diet for A3 weights)
__device__ __forceinline__ float sgprf(float x) {
    return __builtin_bit_cast(float, __builtin_amdgcn_readfirstlane(__builtin_bit_cast(int, x)));
}

// ================= prep: W_cat transpose + zero accumulators =================
__global__ void rits_prep(const float* __restrict__ W_cat, float* __restrict__ ws)
{
    int idx = blockIdx.x * 256 + threadIdx.x;
    if (idx < H_*178) {                      // W_cat [128][178] -> [178][128]
        int j = idx / 178, k = idx - j*178;
        ws[WS_WCATT + k*H_ + j] = W_cat[idx];
    }
    if (idx < T_) ws[WS_MINV + idx] = 0.f;
    if (idx < 2) ws[WS_ACC + idx] = 0.f;
}

// ================= per-step mask sums (coalesced, atomic partials) =================
__global__ void rits_msum(const float* __restrict__ masks, float* __restrict__ ws)
{
    const int tc = blockIdx.x % 7;           // t-chunk of 32 steps
    const int bg = blockIdx.x / 7;           // batch group
    const int t0 = tc * 32;
    const int nt = (t0 + 32 <= T_) ? 32 : (T_ - t0);
    const int ncol = nt * D_;                // 224 or 217
    const int tid = threadIdx.x;
    __shared__ float sums[224];
    float s = 0.f;
    if (tid < ncol) {
        const int bpg = B_ / MS_BG;          // 64
        const float* p = masks + (size_t)bg * bpg * TD_ + (size_t)t0 * D_ + tid;
        #pragma unroll 4
        for (int b = 0; b < bpg; ++b) s += p[(size_t)b * TD_];
    }
    if (tid < 224) sums[tid] = (tid < ncol) ? s : 0.f;
    __syncthreads();
    if (tid < 32) {
        float r = 0.f;
        #pragma unroll
        for (int q = 0; q < 7; ++q) r += sums[tid*7 + q];
        if (t0 + tid < T_) atomicAdd(&ws[WS_MINV + t0 + tid], r);
    }
}

// ================= main scan kernel (MFMA) =================
// Register diet vs r0: gate bias via ext "1.0" column (winf k=14), decay bias
// via dbuf col7=1.0 (wtdf k=7), A3 weights wave-uniform in SGPRs (wave w owns
// feature i=w, lanes 0..15 = batch row).  Target: <=128 unified regs so two
// 8-wave blocks co-reside per CU (grid 512).
// ext layout per batch row (bf16, stride 168): 0..127 h, 128..134 c_c,
// 135..141 m, 142 = 1.0 (bias col), 143..159 = 0.
__global__ __launch_bounds__(NTHR, 4) void rits_main(
    const float* __restrict__ values, const float* __restrict__ masks, const float* __restrict__ deltas,
    const float* __restrict__ W_td_h, const float* __restrict__ b_td_h,
    const float* __restrict__ W_td_x, const float* __restrict__ b_td_x,
    const float* __restrict__ W_hist, const float* __restrict__ b_hist,
    const float* __restrict__ W_feat, const float* __restrict__ b_feat,
    const float* __restrict__ W_comb, const float* __restrict__ b_comb,
    const float* __restrict__ W_ih, const float* __restrict__ W_hh,
    const float* __restrict__ b_ih, const float* __restrict__ b_hh,
    float* __restrict__ ws, float* __restrict__ out)
{
    __shared__ __attribute__((aligned(16))) unsigned short hbuf[NB*168];
    __shared__ __attribute__((aligned(16))) unsigned short dbuf[NB*72];   // d(t+1) bf16; col7=1.0; 8..31=0
    __shared__ __attribute__((aligned(16))) unsigned short whis_lds[16*136]; // W_hist bf16, rows 7..15 = 0
    __shared__ float xs[NB*8], msh[NB*8], dsl[NB*8];
    __shared__ float xh_l[NB*8], xc_l[NB*8], gx_l[NB*8];
    __shared__ float bhist_l[8], tdx_l[8], btdx_l[8];
    __shared__ float impbuf[NB*16*7];       // 16-step imputation buffer (fp32)
    __shared__ float red[8];

    const int tid  = threadIdx.x;
    const int b0   = blockIdx.x * NB;
    const int lane = tid & 63;
    const int w    = tid >> 6;      // wave 0..7
    const int quad = lane >> 4;
    const int l15  = lane & 15;

    // ---- one-time LDS init ----
    for (int i = tid; i < NB*168; i += NTHR) hbuf[i] = 0;
    for (int i = tid; i < NB*72;  i += NTHR) dbuf[i] = 0;
    for (int i = tid; i < 16*136; i += NTHR) {
        int r = i / 136, c = i - r*136;
        whis_lds[i] = (r < 7 && c < 128) ? f2bf(W_hist[r*H_ + c]) : 0;
    }
    for (int i = tid; i < NB*8; i += NTHR) {
        xs[i]=0.f; msh[i]=0.f; dsl[i]=0.f; xh_l[i]=0.f; xc_l[i]=0.f; gx_l[i]=0.f;
    }
    if (tid < 8) {
        bhist_l[tid] = (tid < 7) ? b_hist[tid] : 0.f;
        tdx_l[tid]   = (tid < 7) ? W_td_x[tid*D_ + tid] : 0.f;
        btdx_l[tid]  = (tid < 7) ? b_td_x[tid] : 0.f;
    }
    __syncthreads();                // zeros visible before bias-column pokes
    if (tid < NB) {
        hbuf[tid*168 + 142] = 0x3F80;   // bf16 1.0 -> gate-bias column
        dbuf[tid*72  + 7]   = 0x3F80;   // bf16 1.0 -> decay-bias column
    }

    // ---- persistent weight fragments (per lane) ----
    short8 whhf[4][4];   // [gate c][kstep]  A[j=l15 of tile][k=quad*8+e]
    short8 winf[4];      // ext kstep: k0..6 cc-W, k7..13 m-W, k14 = b_ih+b_hh
    short8 wtdf;         // W_td_h frag: k0..6 = W, k7 = b_td_h
    {
        union UU { short8 v; unsigned short u[8]; } fr;
        #pragma unroll
        for (int c = 0; c < 4; ++c) {
            const int j = (c*8 + w)*16 + l15;
            #pragma unroll
            for (int s = 0; s < 4; ++s) {
                const float* p = W_hh + j*H_ + s*32 + quad*8;
                #pragma unroll
                for (int e = 0; e < 8; ++e) fr.u[e] = f2bf(p[e]);
                whhf[c][s] = fr.v;
            }
            #pragma unroll
            for (int e = 0; e < 8; ++e) {
                int k = quad*8 + e;
                float v = (k < 14) ? W_ih[j*14 + k]
                        : ((k == 14) ? (b_ih[j] + b_hh[j]) : 0.f);
                fr.u[e] = f2bf(v);
            }
            winf[c] = fr.v;
        }
        const int j = w*16 + l15;
        #pragma unroll
        for (int e = 0; e < 8; ++e) {
            int k = quad*8 + e;
            float v = (k < 7) ? W_td_h[j*D_ + k]
                    : ((k == 7) ? b_td_h[j] : 0.f);
            fr.u[e] = f2bf(v);
        }
        wtdf = fr.v;
    }

    // ---- A3 weights: wave-uniform -> SGPRs (wave w handles feature i=w) ----
    const int wu = __builtin_amdgcn_readfirstlane(w);
    const int wc = (wu < 7) ? wu : 6;            // clamp (wave7 unused, avoid OOB)
    float wfr_s[7], wcr_s[14];
    #pragma unroll
    for (int k = 0; k < 7; ++k)  wfr_s[k] = sgprf((k == wc) ? 0.f : W_feat[wc*D_ + k]);
    #pragma unroll
    for (int k = 0; k < 14; ++k) wcr_s[k] = sgprf(W_comb[wc*14 + k]);
    const float bfr_s = sgprf(b_feat[wc]);
    const float bcr_s = sgprf(b_comb[wc]);

    // ---- stager/A3 threads: wave w (<7), lanes 0..15 = batch row ----
    const bool stg = (w < 7) && (quad == 0);
    const int  bb  = l15;
    const long gbase = (long)(b0 + bb)*TD_ + wu;
    float rx = 0.f, rm = 0.f, rd = 0.f;
    if (stg) { rx = values[gbase]; rm = masks[gbase]; rd = deltas[gbase]; }

    float c_st[4] = {0,0,0,0};
    float lacc = 0.f;
    const float* msums = ws + WS_MINV;

    for (int t = 0; t < T_; ++t) {
        if (stg) { xs[bb*8+wu] = rx; msh[bb*8+wu] = rm; dsl[bb*8+wu] = rd; }
        __syncthreads();                       // [S] stage + prev h-writes visible
        float invt = 0.f;
        if (stg) {
            hbuf[bb*168 + 135 + wu] = f2bf(rm);        // m(t) ext (post-[S]: safe vs prev B2)
            invt = rcp_(msums[t] + 1e-5f);
            if (t + 1 < T_) {
                const long g = gbase + (long)(t+1)*D_;
                rx = values[g]; rm = masks[g]; rd = deltas[g];
            }
            dbuf[bb*72 + wu] = f2bf(rd);               // d(t+1) (stale at t=T-1, unused)
        }

        // ---- B1: gate h-part (+ x_h on wave 7). h in hbuf is ALREADY decayed ----
        floatx4 acc[4];
        #pragma unroll
        for (int c = 0; c < 4; ++c) { floatx4 z = {0,0,0,0}; acc[c] = z; }
        floatx4 xh0 = {0,0,0,0};
        #pragma unroll
        for (int s = 0; s < 4; ++s) {
            short8 hb0 = *(const short8*)&hbuf[l15*168 + s*32 + quad*8];
            #pragma unroll
            for (int c = 0; c < 4; ++c)
                acc[c] = MFMA16(whhf[c][s], hb0, acc[c]);
            if (w == 7) {
                short8 wh = *(const short8*)&whis_lds[l15*136 + s*32 + quad*8];
                xh0 = MFMA16(wh, hb0, xh0);
            }
        }
        // wave 7: finish x_h, compute x_c / gamma_x, publish to LDS
        if (w == 7 && quad < 2) {
            const int b = l15;
            #pragma unroll
            for (int r = 0; r < 4; ++r) {
                const int i = quad*4 + r;
                if (i < 7) {
                    float xhv = xh0[r] + bhist_l[i];
                    float x = xs[b*8+i], m = msh[b*8+i], d = dsl[b*8+i];
                    xh_l[b*8+i] = xhv;
                    xc_l[b*8+i] = m*x + (1.f-m)*xhv;
                    gx_l[b*8+i] = __expf(-fmaxf(fmaf(d, tdx_l[i], btdx_l[i]), 0.f));
                }
            }
        }
        __syncthreads();                       // [B] x_h / x_c / gamma_x ready

        // ---- A3 (wave-per-feature): z_h, alpha, c_h, c_c, imputation, loss ----
        if (stg) {
            const int b = bb;
            float zh = bfr_s, al = bcr_s;
            #pragma unroll
            for (int k = 0; k < 7; ++k) zh = fmaf(wfr_s[k], xc_l[b*8+k], zh);
            #pragma unroll
            for (int k = 0; k < 7; ++k) al = fmaf(wcr_s[k], gx_l[b*8+k], al);
            #pragma unroll
            for (int k = 0; k < 7; ++k) al = fmaf(wcr_s[7+k], msh[b*8+k], al);
            const float x = xs[b*8+wu], m = msh[b*8+wu];
            const float xhv = xh_l[b*8+wu];
            const float ch  = al*zh + (1.f-al)*xhv;
            const float cc  = m*x + (1.f-m)*ch;
            impbuf[(b*16 + (t & 15))*7 + wu] = cc;
            hbuf[b*168 + 128 + wu] = f2bf(cc);
            lacc = fmaf((fabsf(x-xhv) + fabsf(x-zh) + fabsf(x-ch)) * m, invt, lacc);
        }
        __syncthreads();                       // [C] c_c ext ready

        // ---- B2: input part (bias arrives via k=14 x col142=1.0) ----
        {
            short8 ib0 = *(const short8*)&hbuf[l15*168 + 128 + quad*8];
            #pragma unroll
            for (int c = 0; c < 4; ++c)
                acc[c] = MFMA16(winf[c], ib0, acc[c]);
        }
        // ---- fused gamma_h(t+1) via MFMA on d(t+1); bias via k=7 x col7=1.0 ----
        floatx4 g0 = {0,0,0,0};
        const bool dec = (t + 1 < T_);
        if (dec) {
            short8 df0 = *(const short8*)&dbuf[l15*72 + quad*8];
            floatx4 z = {0,0,0,0};
            g0 = MFMA16(wtdf, df0, z);
        }
        // ---- LSTM update; write h (pre-decayed for next step) as one b64 ----
        {
            const int b = l15;
            float hnv[4];
            #pragma unroll
            for (int r = 0; r < 4; ++r) {
                float ig = acc[0][r], fg = acc[1][r];
                float gv = acc[2][r], og = acc[3][r];
                float cn = sigm(fg)*c_st[r] + sigm(ig)*tanh_(gv);
                c_st[r] = cn;
                float hn = sigm(og)*tanh_(cn);
                if (dec) hn *= __expf(-fmaxf(g0[r], 0.f));
                hnv[r] = hn;
            }
            uint2 pk;
            pk.x = (unsigned)f2bf(hnv[0]) | ((unsigned)f2bf(hnv[1]) << 16);
            pk.y = (unsigned)f2bf(hnv[2]) | ((unsigned)f2bf(hnv[3]) << 16);
            *(uint2*)&hbuf[b*168 + w*16 + quad*4] = pk;
        }

        // ---- imputation flush (contiguous 28B runs, 16 steps at a time) ----
        if ((t & 15) == 15 || t == T_ - 1) {
            const int t0 = t & ~15;
            const int b  = tid >> 4, c16 = tid & 15;
            if (b < NB && t0 + c16 <= t) {
                float* gp = out + (size_t)OUT_IMP + (size_t)(b0+b)*TD_ + (size_t)(t0+c16)*D_;
                const float* lp = &impbuf[(b*16 + c16)*7];
                #pragma unroll
                for (int e = 0; e < 7; ++e) gp[e] = lp[e];
            }
        }
    }
    __syncthreads();

    // ---- x_loss partial reduction ----
    for (int off = 32; off > 0; off >>= 1) lacc += __shfl_down(lacc, off, 64);
    if ((tid & 63) == 0) red[tid >> 6] = lacc;
    __syncthreads();
    if (tid == 0) {
        float s = 0.f;
        #pragma unroll
        for (int q = 0; q < 8; ++q) s += red[q];
        atomicAdd(&ws[WS_ACC], s);
    }
    // ---- final h -> workspace (fp32) ----
    for (int i = tid; i < NB*H_; i += NTHR) {
        int b = i >> 7, j = i & 127;
        ws[WS_HFIN + (size_t)(b0+b)*H_ + j] = bf2f(hbuf[b*168 + j]);
    }
}

// ================= classification head =================
__global__ __launch_bounds__(128) void rits_head(
    const float* __restrict__ probs, const float* __restrict__ ancillary, const int* __restrict__ labels,
    const float* __restrict__ W_anc, const float* __restrict__ b_anc,
    const float* __restrict__ b_cat,
    const float* __restrict__ W_out, const float* __restrict__ b_out,
    float* __restrict__ ws, float* __restrict__ out)
{
    __shared__ float hb[MB*H_];
    __shared__ float ancl[MB*52];
    __shared__ float hc[MB*H_];
    __shared__ float lg[MB*32];
    __shared__ float smx[MB], sinv[MB], ysum[MB];
    __shared__ float sq[MB*32];
    const int tid = threadIdx.x;
    const int bb0 = blockIdx.x * MB;

    for (int i = tid; i < MB*H_; i += 128) hb[i] = ws[WS_HFIN + (size_t)bb0*H_ + i];
    for (int i = tid; i < MB*E_; i += 128) {
        int b = i / E_, e = i - b*E_;
        float s = b_anc[e];
        #pragma unroll
        for (int a = 0; a < A_; ++a) s = fmaf(ancillary[(bb0+b)*A_ + a], W_anc[e*A_ + a], s);
        ancl[b*52+e] = fmaxf(s, 0.f);
    }
    __syncthreads();
    {
        const int j = tid;
        float s[MB];
        #pragma unroll
        for (int b = 0; b < MB; ++b) s[b] = b_cat[j];
        const float* wc = ws + WS_WCATT;
        for (int k = 0; k < H_; ++k) {
            float wv = wc[k*H_ + j];
            #pragma unroll
            for (int b = 0; b < MB; ++b) s[b] = fmaf(hb[b*H_+k], wv, s[b]);
        }
        for (int k = 0; k < E_; ++k) {
            float wv = wc[(H_+k)*H_ + j];
            #pragma unroll
            for (int b = 0; b < MB; ++b) s[b] = fmaf(ancl[b*52+k], wv, s[b]);
        }
        #pragma unroll
        for (int b = 0; b < MB; ++b) hc[b*H_+j] = fmaxf(s[b], 0.f);
    }
    __syncthreads();
    for (int i = tid; i < MB*O_; i += 128) {
        int b = i / O_, o = i - b*O_;
        float s = b_out[o];
        for (int k = 0; k < H_; ++k) s = fmaf(hc[b*H_+k], W_out[o*H_+k], s);
        lg[b*32+o] = s;
    }
    __syncthreads();
    if (tid < MB) {
        float mx = -1e30f;
        for (int o = 0; o < O_; ++o) mx = fmaxf(mx, lg[tid*32+o]);
        float se = 0.f;
        for (int o = 0; o < O_; ++o) se += __expf(lg[tid*32+o] - mx);
        smx[tid] = mx; sinv[tid] = 1.f / se;
    }
    __syncthreads();
    for (int i = tid; i < MB*O_; i += 128) {
        int b = i / O_, o = i - b*O_;
        float y = __expf(lg[b*32+o] - smx[b]) * sinv[b];
        out[OUT_YH + (size_t)(bb0+b)*O_ + o] = y;
        float d = y - probs[(size_t)(bb0+b)*O_ + o];
        sq[b*32+o] = d*d;
    }
    __syncthreads();
    if (tid < MB) {
        float s = 0.f;
        for (int o = 0; o < O_; ++o) s += sq[tid*32+o];
        ysum[tid] = s;
        out[OUT_LAB + bb0 + tid] = (float)labels[bb0 + tid];
    }
    __syncthreads();
    if (tid == 0) {
        float s = 0.f;
        #pragma unroll
        for (int b = 0; b < MB; ++b) s += ysum[b];
        atomicAdd(&ws[WS_ACC+1], s);
    }
}

// ================= finalize scalars =================
__global__ void rits_fin(const float* __restrict__ ws, float* __restrict__ out)
{
    if (blockIdx.x == 0 && threadIdx.x == 0) {
        float xl = ws[WS_ACC] * 0.3f;
        float yl = ws[WS_ACC+1] * (1.0f / (8192.0f + 1e-5f));
        out[0] = xl; out[1] = yl; out[2] = xl + yl;
    }
}

extern "C" void kernel_launch(void* const* d_in, const int* in_sizes, int n_in,
                              void* d_out, int out_size, void* d_ws, size_t ws_size,
                              hipStream_t stream)
{
    const float* values = (const float*)d_in[0];
    const float* masks  = (const float*)d_in[1];
    const float* deltas = (const float*)d_in[2];
    const float* probs  = (const float*)d_in[3];
    const float* ancil  = (const float*)d_in[4];
    const int*   labels = (const int*)  d_in[5];
    const float* W_td_h = (const float*)d_in[6];
    const float* b_td_h = (const float*)d_in[7];
    const float* W_td_x = (const float*)d_in[8];
    const float* b_td_x = (const float*)d_in[9];
    const float* W_hist = (const float*)d_in[10];
    const float* b_hist = (const float*)d_in[11];
    const float* W_feat = (const float*)d_in[12];
    const float* b_feat = (const float*)d_in[13];
    const float* W_comb = (const float*)d_in[14];
    const float* b_comb = (const float*)d_in[15];
    const float* W_ih   = (const float*)d_in[16];
    const float* W_hh   = (const float*)d_in[17];
    const float* b_ih   = (const float*)d_in[18];
    const float* b_hh   = (const float*)d_in[19];
    const float* W_anc  = (const float*)d_in[20];
    const float* b_anc  = (const float*)d_in[21];
    const float* W_cat  = (const float*)d_in[22];
    const float* b_cat  = (const float*)d_in[23];
    const float* W_out  = (const float*)d_in[24];
    const float* b_out  = (const float*)d_in[25];
    float* ws  = (float*)d_ws;
    float* out = (float*)d_out;

    hipLaunchKernelGGL(rits_prep, dim3((H_*178 + 255)/256), dim3(256), 0, stream, W_cat, ws);
    hipLaunchKernelGGL(rits_msum, dim3(7*MS_BG), dim3(256), 0, stream, masks, ws);
    hipLaunchKernelGGL(rits_main, dim3(B_/NB), dim3(NTHR), 0, stream,
                       values, masks, deltas, W_td_h, b_td_h, W_td_x, b_td_x,
                       W_hist, b_hist, W_feat, b_feat, W_comb, b_comb,
                       W_ih, W_hh, b_ih, b_hh, ws, out);
    hipLaunchKernelGGL(rits_head, dim3(B_/MB), dim3(128), 0, stream,
                       probs, ancil, labels, W_anc, b_anc, b_cat, W_out, b_out, ws, out);
    hipLaunchKernelGGL(rits_fin, dim3(1), dim3(1), 0, stream, ws, out);
}

// Round 3
// 1271.257 us; speedup vs baseline: 2.7736x; 1.3671x over previous
//
#include <hip/hip_runtime.h>
#include <math.h>

// ---------------- problem constants ----------------
#define B_ 8192
#define T_ 223
#define D_ 7
#define H_ 128
#define E_ 50
#define O_ 29
#define A_ 9
#define TD_ (T_*D_)     // 1561
#define NB 16           // batch rows per block -> grid 512 = 2 blocks/CU
#define NTHR 512
#define MB 8            // batch rows per block (head kernel)
#define MS_BG 128       // msum batch groups

// ---------------- workspace layout (float offsets) ----------------
#define WS_MINV  0                            // raw msum_t sums, T floats
#define WS_ACC   (WS_MINV + T_)               // [0]=x_loss raw sum, [1]=y_loss raw sum
#define WS_WCATT (WS_ACC + 2)                 // [178][128] transposed W_cat
#define WS_HFIN  (WS_WCATT + 178*H_)          // final h, [B][128] fp32

// ---------------- output layout (floats) ----------------
#define OUT_YH  3
#define OUT_IMP (OUT_YH + B_*O_)              // 237571
#define OUT_LAB (OUT_IMP + B_*T_*D_)          // 13025283

typedef __attribute__((ext_vector_type(8))) short short8;   // 8 bf16 = 4 VGPRs
typedef __attribute__((ext_vector_type(4))) float floatx4;
#define MFMA16(Av,Bv,Cv) __builtin_amdgcn_mfma_f32_16x16x32_bf16((Av),(Bv),(Cv),0,0,0)

__device__ __forceinline__ unsigned short f2bf(float f) {   // RNE fp32->bf16
    unsigned int u = __builtin_bit_cast(unsigned int, f);
    return (unsigned short)((u + 0x7FFFu + ((u >> 16) & 1u)) >> 16);
}
__device__ __forceinline__ float bf2f(unsigned short s) {
    unsigned int u = ((unsigned int)s) << 16;
    return __builtin_bit_cast(float, u);
}
__device__ __forceinline__ float rcp_(float x)  { return __builtin_amdgcn_rcpf(x); }
__device__ __forceinline__ float sigm(float x)  { return rcp_(1.f + __expf(-x)); }
__device__ __forceinline__ float tanh_(float x) { return 1.f - 2.f*rcp_(1.f + __expf(2.f*x)); }
// force a wave-uniform float into an SGPR (register-diet for A3 weights)
__device__ __forceinline__ float sgprf(float x) {
    return __builtin_bit_cast(float, __builtin_amdgcn_readfirstlane(__builtin_bit_cast(int, x)));
}

// ================= prep: W_cat transpose + zero accumulators =================
__global__ void rits_prep(const float* __restrict__ W_cat, float* __restrict__ ws)
{
    int idx = blockIdx.x * 256 + threadIdx.x;
    if (idx < H_*178) {                      // W_cat [128][178] -> [178][128]
        int j = idx / 178, k = idx - j*178;
        ws[WS_WCATT + k*H_ + j] = W_cat[idx];
    }
    if (idx < T_) ws[WS_MINV + idx] = 0.f;
    if (idx < 2) ws[WS_ACC + idx] = 0.f;
}

// ================= per-step mask sums (coalesced, atomic partials) =================
__global__ void rits_msum(const float* __restrict__ masks, float* __restrict__ ws)
{
    const int tc = blockIdx.x % 7;           // t-chunk of 32 steps
    const int bg = blockIdx.x / 7;           // batch group
    const int t0 = tc * 32;
    const int nt = (t0 + 32 <= T_) ? 32 : (T_ - t0);
    const int ncol = nt * D_;                // 224 or 217
    const int tid = threadIdx.x;
    __shared__ float sums[224];
    float s = 0.f;
    if (tid < ncol) {
        const int bpg = B_ / MS_BG;          // 64
        const float* p = masks + (size_t)bg * bpg * TD_ + (size_t)t0 * D_ + tid;
        #pragma unroll 4
        for (int b = 0; b < bpg; ++b) s += p[(size_t)b * TD_];
    }
    if (tid < 224) sums[tid] = (tid < ncol) ? s : 0.f;
    __syncthreads();
    if (tid < 32) {
        float r = 0.f;
        #pragma unroll
        for (int q = 0; q < 7; ++q) r += sums[tid*7 + q];
        if (t0 + tid < T_) atomicAdd(&ws[WS_MINV + t0 + tid], r);
    }
}

// ================= main scan kernel (MFMA) =================
// Register budget theory: under launch_bounds(512,4) the backend splits the
// 128-reg unified file 64 arch / 64 acc.  whhf (64 regs, MFMA A-operands)
// lives on the AGPR side; everything else must fit in 64 arch VGPRs.  So
// winf/wtdf are NOT register-resident: their A-fragments are re-read from
// LDS (wext_lds / wtd_lds) once per step (5 extra ds_read_b128/wave/step).
// ext layout per batch row (bf16, stride 168): 0..127 h, 128..134 c_c,
// 135..141 m, 142 = 1.0 (bias col), 143..159 = 0.
__global__ __launch_bounds__(NTHR, 4) void rits_main(
    const float* __restrict__ values, const float* __restrict__ masks, const float* __restrict__ deltas,
    const float* __restrict__ W_td_h, const float* __restrict__ b_td_h,
    const float* __restrict__ W_td_x, const float* __restrict__ b_td_x,
    const float* __restrict__ W_hist, const float* __restrict__ b_hist,
    const float* __restrict__ W_feat, const float* __restrict__ b_feat,
    const float* __restrict__ W_comb, const float* __restrict__ b_comb,
    const float* __restrict__ W_ih, const float* __restrict__ W_hh,
    const float* __restrict__ b_ih, const float* __restrict__ b_hh,
    float* __restrict__ ws, float* __restrict__ out)
{
    __shared__ __attribute__((aligned(16))) unsigned short hbuf[NB*168];
    __shared__ __attribute__((aligned(16))) unsigned short dbuf[NB*72];   // d(t+1) bf16; col7=1.0; 8..31=0
    __shared__ __attribute__((aligned(16))) unsigned short whis_lds[16*136]; // W_hist bf16, rows 7..15 = 0
    __shared__ __attribute__((aligned(16))) unsigned short wext_lds[512*24]; // W_ih ext: k0..13 W, k14 bias, k15..23 0
    __shared__ __attribute__((aligned(16))) unsigned short wtd_lds[128*8];   // W_td_h: k0..6 W, k7 bias
    __shared__ __attribute__((aligned(16))) unsigned short zpad[8];          // 16B of zeros (broadcast reads)
    __shared__ float xs[NB*8], msh[NB*8], dsl[NB*8];
    __shared__ float xh_l[NB*8], xc_l[NB*8], gx_l[NB*8];
    __shared__ float bhist_l[8], tdx_l[8], btdx_l[8];
    __shared__ float impbuf[NB*16*7];       // 16-step imputation buffer (fp32)
    __shared__ float red[8];

    const int tid  = threadIdx.x;
    const int b0   = blockIdx.x * NB;
    const int lane = tid & 63;
    const int w    = tid >> 6;      // wave 0..7
    const int quad = lane >> 4;
    const int l15  = lane & 15;

    // ---- one-time LDS init ----
    for (int i = tid; i < NB*168; i += NTHR) hbuf[i] = 0;
    for (int i = tid; i < NB*72;  i += NTHR) dbuf[i] = 0;
    for (int i = tid; i < 16*136; i += NTHR) {
        int r = i / 136, c = i - r*136;
        whis_lds[i] = (r < 7 && c < 128) ? f2bf(W_hist[r*H_ + c]) : 0;
    }
    for (int i = tid; i < 512*24; i += NTHR) {
        int j = i / 24, k = i - j*24;
        float v = (k < 14) ? W_ih[j*14 + k]
                : ((k == 14) ? (b_ih[j] + b_hh[j]) : 0.f);
        wext_lds[i] = f2bf(v);
    }
    for (int i = tid; i < 128*8; i += NTHR) {
        int j = i >> 3, k = i & 7;
        float v = (k < 7) ? W_td_h[j*D_ + k] : b_td_h[j];
        wtd_lds[i] = f2bf(v);
    }
    if (tid < 8) {
        zpad[tid] = 0;
        bhist_l[tid] = (tid < 7) ? b_hist[tid] : 0.f;
        tdx_l[tid]   = (tid < 7) ? W_td_x[tid*D_ + tid] : 0.f;
        btdx_l[tid]  = (tid < 7) ? b_td_x[tid] : 0.f;
    }
    for (int i = tid; i < NB*8; i += NTHR) {
        xs[i]=0.f; msh[i]=0.f; dsl[i]=0.f; xh_l[i]=0.f; xc_l[i]=0.f; gx_l[i]=0.f;
    }
    __syncthreads();                // zeros visible before bias-column pokes
    if (tid < NB) {
        hbuf[tid*168 + 142] = 0x3F80;   // bf16 1.0 -> gate-bias column
        dbuf[tid*72  + 7]   = 0x3F80;   // bf16 1.0 -> decay-bias column
    }

    // ---- persistent W_hh fragments (AGPR side) ----
    short8 whhf[4][4];   // [gate c][kstep]  A[j=l15 of tile][k=quad*8+e]
    {
        union UU { short8 v; unsigned short u[8]; } fr;
        #pragma unroll
        for (int c = 0; c < 4; ++c) {
            const int j = (c*8 + w)*16 + l15;
            #pragma unroll
            for (int s = 0; s < 4; ++s) {
                const float* p = W_hh + j*H_ + s*32 + quad*8;
                #pragma unroll
                for (int e = 0; e < 8; ++e) fr.u[e] = f2bf(p[e]);
                whhf[c][s] = fr.v;
            }
        }
    }

    // ---- A3 weights: wave-uniform -> SGPRs (wave w handles feature i=w) ----
    const int wu = __builtin_amdgcn_readfirstlane(w);
    const int wc = (wu < 7) ? wu : 6;            // clamp (wave7 unused, avoid OOB)
    float wfr_s[7], wcr_s[14];
    #pragma unroll
    for (int k = 0; k < 7; ++k)  wfr_s[k] = sgprf((k == wc) ? 0.f : W_feat[wc*D_ + k]);
    #pragma unroll
    for (int k = 0; k < 14; ++k) wcr_s[k] = sgprf(W_comb[wc*14 + k]);
    const float bfr_s = sgprf(b_feat[wc]);
    const float bcr_s = sgprf(b_comb[wc]);

    // ---- stager/A3 threads: wave w (<7), lanes 0..15 = batch row ----
    const bool stg = (w < 7) && (quad == 0);
    const int  bb  = l15;
    const long gbase = (long)(b0 + bb)*TD_ + wu;
    float rx = 0.f, rm = 0.f, rd = 0.f;
    if (stg) { rx = values[gbase]; rm = masks[gbase]; rd = deltas[gbase]; }

    float c_st[4] = {0,0,0,0};
    float lacc = 0.f;
    const float* msums = ws + WS_MINV;

    for (int t = 0; t < T_; ++t) {
        if (stg) { xs[bb*8+wu] = rx; msh[bb*8+wu] = rm; dsl[bb*8+wu] = rd; }
        __syncthreads();                       // [S] stage + prev h-writes visible
        float invt = 0.f;
        if (stg) {
            hbuf[bb*168 + 135 + wu] = f2bf(rm);        // m(t) ext (post-[S]: safe vs prev B2)
            invt = rcp_(msums[t] + 1e-5f);
            if (t + 1 < T_) {
                const long g = gbase + (long)(t+1)*D_;
                rx = values[g]; rm = masks[g]; rd = deltas[g];
            }
            dbuf[bb*72 + wu] = f2bf(rd);               // d(t+1) (stale at t=T-1, unused)
        }

        // ---- B1: gate h-part (+ x_h on wave 7). h in hbuf is ALREADY decayed ----
        floatx4 acc[4];
        #pragma unroll
        for (int c = 0; c < 4; ++c) { floatx4 z = {0,0,0,0}; acc[c] = z; }
        floatx4 xh0 = {0,0,0,0};
        #pragma unroll
        for (int s = 0; s < 4; ++s) {
            short8 hb0 = *(const short8*)&hbuf[l15*168 + s*32 + quad*8];
            #pragma unroll
            for (int c = 0; c < 4; ++c)
                acc[c] = MFMA16(whhf[c][s], hb0, acc[c]);
            if (w == 7) {
                short8 wh = *(const short8*)&whis_lds[l15*136 + s*32 + quad*8];
                xh0 = MFMA16(wh, hb0, xh0);
            }
        }
        // wave 7: finish x_h, compute x_c / gamma_x, publish to LDS
        if (w == 7 && quad < 2) {
            const int b = l15;
            #pragma unroll
            for (int r = 0; r < 4; ++r) {
                const int i = quad*4 + r;
                if (i < 7) {
                    float xhv = xh0[r] + bhist_l[i];
                    float x = xs[b*8+i], m = msh[b*8+i], d = dsl[b*8+i];
                    xh_l[b*8+i] = xhv;
                    xc_l[b*8+i] = m*x + (1.f-m)*xhv;
                    gx_l[b*8+i] = __expf(-fmaxf(fmaf(d, tdx_l[i], btdx_l[i]), 0.f));
                }
            }
        }
        __syncthreads();                       // [B] x_h / x_c / gamma_x ready

        // ---- A3 (wave-per-feature): z_h, alpha, c_h, c_c, imputation, loss ----
        if (stg) {
            const int b = bb;
            float zh = bfr_s, al = bcr_s;
            #pragma unroll
            for (int k = 0; k < 7; ++k) zh = fmaf(wfr_s[k], xc_l[b*8+k], zh);
            #pragma unroll
            for (int k = 0; k < 7; ++k) al = fmaf(wcr_s[k], gx_l[b*8+k], al);
            #pragma unroll
            for (int k = 0; k < 7; ++k) al = fmaf(wcr_s[7+k], msh[b*8+k], al);
            const float x = xs[b*8+wu], m = msh[b*8+wu];
            const float xhv = xh_l[b*8+wu];
            const float ch  = al*zh + (1.f-al)*xhv;
            const float cc  = m*x + (1.f-m)*ch;
            impbuf[(b*16 + (t & 15))*7 + wu] = cc;
            hbuf[b*168 + 128 + wu] = f2bf(cc);
            lacc = fmaf((fabsf(x-xhv) + fabsf(x-zh) + fabsf(x-ch)) * m, invt, lacc);
        }
        __syncthreads();                       // [C] c_c ext ready

        // ---- B2: input part; A-frags streamed from LDS (quads>=2 read zeros) ----
        {
            short8 ib0 = *(const short8*)&hbuf[l15*168 + 128 + quad*8];
            #pragma unroll
            for (int c = 0; c < 4; ++c) {
                const unsigned short* ap = (quad < 2)
                    ? &wext_lds[((c*8 + w)*16 + l15)*24 + quad*8] : zpad;
                short8 af = *(const short8*)ap;
                acc[c] = MFMA16(af, ib0, acc[c]);
            }
        }
        // ---- fused gamma_h(t+1) via MFMA on d(t+1); bias via k=7 x col7=1.0 ----
        floatx4 g0 = {0,0,0,0};
        const bool dec = (t + 1 < T_);
        if (dec) {
            const unsigned short* ap = (quad == 0)
                ? &wtd_lds[(w*16 + l15)*8] : zpad;
            short8 af = *(const short8*)ap;
            short8 df0 = *(const short8*)&dbuf[l15*72 + quad*8];
            floatx4 z = {0,0,0,0};
            g0 = MFMA16(af, df0, z);
        }
        // ---- LSTM update; write h (pre-decayed for next step) as one b64 ----
        {
            const int b = l15;
            float hnv[4];
            #pragma unroll
            for (int r = 0; r < 4; ++r) {
                float ig = acc[0][r], fg = acc[1][r];
                float gv = acc[2][r], og = acc[3][r];
                float cn = sigm(fg)*c_st[r] + sigm(ig)*tanh_(gv);
                c_st[r] = cn;
                float hn = sigm(og)*tanh_(cn);
                if (dec) hn *= __expf(-fmaxf(g0[r], 0.f));
                hnv[r] = hn;
            }
            uint2 pk;
            pk.x = (unsigned)f2bf(hnv[0]) | ((unsigned)f2bf(hnv[1]) << 16);
            pk.y = (unsigned)f2bf(hnv[2]) | ((unsigned)f2bf(hnv[3]) << 16);
            *(uint2*)&hbuf[b*168 + w*16 + quad*4] = pk;
        }

        // ---- imputation flush (contiguous 28B runs, 16 steps at a time) ----
        if ((t & 15) == 15 || t == T_ - 1) {
            const int t0 = t & ~15;
            const int b  = tid >> 4, c16 = tid & 15;
            if (b < NB && t0 + c16 <= t) {
                float* gp = out + (size_t)OUT_IMP + (size_t)(b0+b)*TD_ + (size_t)(t0+c16)*D_;
                const float* lp = &impbuf[(b*16 + c16)*7];
                #pragma unroll
                for (int e = 0; e < 7; ++e) gp[e] = lp[e];
            }
        }
    }
    __syncthreads();

    // ---- x_loss partial reduction ----
    for (int off = 32; off > 0; off >>= 1) lacc += __shfl_down(lacc, off, 64);
    if ((tid & 63) == 0) red[tid >> 6] = lacc;
    __syncthreads();
    if (tid == 0) {
        float s = 0.f;
        #pragma unroll
        for (int q = 0; q < 8; ++q) s += red[q];
        atomicAdd(&ws[WS_ACC], s);
    }
    // ---- final h -> workspace (fp32) ----
    for (int i = tid; i < NB*H_; i += NTHR) {
        int b = i >> 7, j = i & 127;
        ws[WS_HFIN + (size_t)(b0+b)*H_ + j] = bf2f(hbuf[b*168 + j]);
    }
}

// ================= classification head =================
__global__ __launch_bounds__(128) void rits_head(
    const float* __restrict__ probs, const float* __restrict__ ancillary, const int* __restrict__ labels,
    const float* __restrict__ W_anc, const float* __restrict__ b_anc,
    const float* __restrict__ b_cat,
    const float* __restrict__ W_out, const float* __restrict__ b_out,
    float* __restrict__ ws, float* __restrict__ out)
{
    __shared__ float hb[MB*H_];
    __shared__ float ancl[MB*52];
    __shared__ float hc[MB*H_];
    __shared__ float lg[MB*32];
    __shared__ float smx[MB], sinv[MB], ysum[MB];
    __shared__ float sq[MB*32];
    const int tid = threadIdx.x;
    const int bb0 = blockIdx.x * MB;

    for (int i = tid; i < MB*H_; i += 128) hb[i] = ws[WS_HFIN + (size_t)bb0*H_ + i];
    for (int i = tid; i < MB*E_; i += 128) {
        int b = i / E_, e = i - b*E_;
        float s = b_anc[e];
        #pragma unroll
        for (int a = 0; a < A_; ++a) s = fmaf(ancillary[(bb0+b)*A_ + a], W_anc[e*A_ + a], s);
        ancl[b*52+e] = fmaxf(s, 0.f);
    }
    __syncthreads();
    {
        const int j = tid;
        float s[MB];
        #pragma unroll
        for (int b = 0; b < MB; ++b) s[b] = b_cat[j];
        const float* wc = ws + WS_WCATT;
        for (int k = 0; k < H_; ++k) {
            float wv = wc[k*H_ + j];
            #pragma unroll
            for (int b = 0; b < MB; ++b) s[b] = fmaf(hb[b*H_+k], wv, s[b]);
        }
        for (int k = 0; k < E_; ++k) {
            float wv = wc[(H_+k)*H_ + j];
            #pragma unroll
            for (int b = 0; b < MB; ++b) s[b] = fmaf(ancl[b*52+k], wv, s[b]);
        }
        #pragma unroll
        for (int b = 0; b < MB; ++b) hc[b*H_+j] = fmaxf(s[b], 0.f);
    }
    __syncthreads();
    for (int i = tid; i < MB*O_; i += 128) {
        int b = i / O_, o = i - b*O_;
        float s = b_out[o];
        for (int k = 0; k < H_; ++k) s = fmaf(hc[b*H_+k], W_out[o*H_+k], s);
        lg[b*32+o] = s;
    }
    __syncthreads();
    if (tid < MB) {
        float mx = -1e30f;
        for (int o = 0; o < O_; ++o) mx = fmaxf(mx, lg[tid*32+o]);
        float se = 0.f;
        for (int o = 0; o < O_; ++o) se += __expf(lg[tid*32+o] - mx);
        smx[tid] = mx; sinv[tid] = 1.f / se;
    }
    __syncthreads();
    for (int i = tid; i < MB*O_; i += 128) {
        int b = i / O_, o = i - b*O_;
        float y = __expf(lg[b*32+o] - smx[b]) * sinv[b];
        out[OUT_YH + (size_t)(bb0+b)*O_ + o] = y;
        float d = y - probs[(size_t)(bb0+b)*O_ + o];
        sq[b*32+o] = d*d;
    }
    __syncthreads();
    if (tid < MB) {
        float s = 0.f;
        for (int o = 0; o < O_; ++o) s += sq[tid*32+o];
        ysum[tid] = s;
        out[OUT_LAB + bb0 + tid] = (float)labels[bb0 + tid];
    }
    __syncthreads();
    if (tid == 0) {
        float s = 0.f;
        #pragma unroll
        for (int b = 0; b < MB; ++b) s += ysum[b];
        atomicAdd(&ws[WS_ACC+1], s);
    }
}

// ================= finalize scalars =================
__global__ void rits_fin(const float* __restrict__ ws, float* __restrict__ out)
{
    if (blockIdx.x == 0 && threadIdx.x == 0) {
        float xl = ws[WS_ACC] * 0.3f;
        float yl = ws[WS_ACC+1] * (1.0f / (8192.0f + 1e-5f));
        out[0] = xl; out[1] = yl; out[2] = xl + yl;
    }
}

extern "C" void kernel_launch(void* const* d_in, const int* in_sizes, int n_in,
                              void* d_out, int out_size, void* d_ws, size_t ws_size,
                              hipStream_t stream)
{
    const float* values = (const float*)d_in[0];
    const float* masks  = (const float*)d_in[1];
    const float* deltas = (const float*)d_in[2];
    const float* probs  = (const float*)d_in[3];
    const float* ancil  = (const float*)d_in[4];
    const int*   labels = (const int*)  d_in[5];
    const float* W_td_h = (const float*)d_in[6];
    const float* b_td_h = (const float*)d_in[7];
    const float* W_td_x = (const float*)d_in[8];
    const float* b_td_x = (const float*)d_in[9];
    const float* W_hist = (const float*)d_in[10];
    const float* b_hist = (const float*)d_in[11];
    const float* W_feat = (const float*)d_in[12];
    const float* b_feat = (const float*)d_in[13];
    const float* W_comb = (const float*)d_in[14];
    const float* b_comb = (const float*)d_in[15];
    const float* W_ih   = (const float*)d_in[16];
    const float* W_hh   = (const float*)d_in[17];
    const float* b_ih   = (const float*)d_in[18];
    const float* b_hh   = (const float*)d_in[19];
    const float* W_anc  = (const float*)d_in[20];
    const float* b_anc  = (const float*)d_in[21];
    const float* W_cat  = (const float*)d_in[22];
    const float* b_cat  = (const float*)d_in[23];
    const float* W_out  = (const float*)d_in[24];
    const float* b_out  = (const float*)d_in[25];
    float* ws  = (float*)d_ws;
    float* out = (float*)d_out;

    hipLaunchKernelGGL(rits_prep, dim3((H_*178 + 255)/256), dim3(256), 0, stream, W_cat, ws);
    hipLaunchKernelGGL(rits_msum, dim3(7*MS_BG), dim3(256), 0, stream, masks, ws);
    hipLaunchKernelGGL(rits_main, dim3(B_/NB), dim3(NTHR), 0, stream,
                       values, masks, deltas, W_td_h, b_td_h, W_td_x, b_td_x,
                       W_hist, b_hist, W_feat, b_feat, W_comb, b_comb,
                       W_ih, W_hh, b_ih, b_hh, ws, out);
    hipLaunchKernelGGL(rits_head, dim3(B_/MB), dim3(128), 0, stream,
                       probs, ancil, labels, W_anc, b_anc, b_cat, W_out, b_out, ws, out);
    hipLaunchKernelGGL(rits_fin, dim3(1), dim3(1), 0, stream, ws, out);
}

// Round 4
// 933.829 us; speedup vs baseline: 3.7758x; 1.3613x over previous
//
#include <hip/hip_runtime.h>
#include <math.h>

// ---------------- problem constants ----------------
#define B_ 8192
#define T_ 223
#define D_ 7
#define H_ 128
#define E_ 50
#define O_ 29
#define A_ 9
#define TD_ (T_*D_)     // 1561
#define NB 32           // batch rows per block (main kernel) -> grid 256 = 1 block/CU
#define NTHR 512
#define MB 8            // batch rows per block (head kernel)
#define MS_BG 128       // msum batch groups

// ---------------- workspace layout (float offsets) ----------------
#define WS_MINV  0                            // raw msum_t sums, T floats
#define WS_ACC   (WS_MINV + T_)               // [0]=x_loss raw sum, [1]=y_loss raw sum
#define WS_WCATT (WS_ACC + 2)                 // [178][128] transposed W_cat
#define WS_HFIN  (WS_WCATT + 178*H_)          // final h, [B][128] fp32

// ---------------- output layout (floats) ----------------
#define OUT_YH  3
#define OUT_IMP (OUT_YH + B_*O_)              // 237571
#define OUT_LAB (OUT_IMP + B_*T_*D_)          // 13025283

typedef __attribute__((ext_vector_type(8))) short short8;   // 8 bf16 = 4 VGPRs
typedef __attribute__((ext_vector_type(4))) float floatx4;
#define MFMA16(Av,Bv,Cv) __builtin_amdgcn_mfma_f32_16x16x32_bf16((Av),(Bv),(Cv),0,0,0)

__device__ __forceinline__ unsigned short f2bf(float f) {   // RNE fp32->bf16
    unsigned int u = __builtin_bit_cast(unsigned int, f);
    return (unsigned short)((u + 0x7FFFu + ((u >> 16) & 1u)) >> 16);
}
__device__ __forceinline__ float bf2f(unsigned short s) {
    unsigned int u = ((unsigned int)s) << 16;
    return __builtin_bit_cast(float, u);
}
__device__ __forceinline__ float rcp_(float x)  { return __builtin_amdgcn_rcpf(x); }
__device__ __forceinline__ float sigm(float x)  { return rcp_(1.f + __expf(-x)); }
__device__ __forceinline__ float tanh_(float x) { return 1.f - 2.f*rcp_(1.f + __expf(2.f*x)); }

// ================= prep: W_cat transpose + zero accumulators =================
__global__ void rits_prep(const float* __restrict__ W_cat, float* __restrict__ ws)
{
    int idx = blockIdx.x * 256 + threadIdx.x;
    if (idx < H_*178) {                      // W_cat [128][178] -> [178][128]
        int j = idx / 178, k = idx - j*178;
        ws[WS_WCATT + k*H_ + j] = W_cat[idx];
    }
    if (idx < T_) ws[WS_MINV + idx] = 0.f;
    if (idx < 2) ws[WS_ACC + idx] = 0.f;
}

// ================= per-step mask sums (coalesced, atomic partials) =================
__global__ void rits_msum(const float* __restrict__ masks, float* __restrict__ ws)
{
    const int tc = blockIdx.x % 7;           // t-chunk of 32 steps
    const int bg = blockIdx.x / 7;           // batch group
    const int t0 = tc * 32;
    const int nt = (t0 + 32 <= T_) ? 32 : (T_ - t0);
    const int ncol = nt * D_;                // 224 or 217
    const int tid = threadIdx.x;
    __shared__ float sums[224];
    float s = 0.f;
    if (tid < ncol) {
        const int bpg = B_ / MS_BG;          // 64
        const float* p = masks + (size_t)bg * bpg * TD_ + (size_t)t0 * D_ + tid;
        #pragma unroll 4
        for (int b = 0; b < bpg; ++b) s += p[(size_t)b * TD_];
    }
    if (tid < 224) sums[tid] = (tid < ncol) ? s : 0.f;
    __syncthreads();
    if (tid < 32) {
        float r = 0.f;
        #pragma unroll
        for (int q = 0; q < 7; ++q) r += sums[tid*7 + q];
        if (t0 + tid < T_) atomicAdd(&ws[WS_MINV + t0 + tid], r);
    }
}

// ================= main scan kernel (MFMA) =================
// R0 skeleton (proven 777us, 128 VGPR no-spill at launch_bounds(512,2)):
// all A-fragments + biases register-resident, 1 block/CU.  LDS-cycle cuts:
// (1) h written as uint2 (2x ds_write_b64 vs 8x b16 per wave),
// (2) decay MFMA hoisted into the [B]->[C] window (dbuf written at prefetch
//     time) so it overlaps the 224-thread A3 phase instead of serializing
//     after [C].
__global__ __launch_bounds__(NTHR, 2) void rits_main(
    const float* __restrict__ values, const float* __restrict__ masks, const float* __restrict__ deltas,
    const float* __restrict__ W_td_h, const float* __restrict__ b_td_h,
    const float* __restrict__ W_td_x, const float* __restrict__ b_td_x,
    const float* __restrict__ W_hist, const float* __restrict__ b_hist,
    const float* __restrict__ W_feat, const float* __restrict__ b_feat,
    const float* __restrict__ W_comb, const float* __restrict__ b_comb,
    const float* __restrict__ W_ih, const float* __restrict__ W_hh,
    const float* __restrict__ b_ih, const float* __restrict__ b_hh,
    float* __restrict__ ws, float* __restrict__ out)
{
    // B-operand buffer: rows=batch(32), cols bf16: 0..127=h, 128..134=c_c,
    // 135..141=m, 142..159=0. Row stride 168 bf16 = 336B (16B-aligned)
    __shared__ __attribute__((aligned(16))) unsigned short hbuf[NB*168];
    __shared__ __attribute__((aligned(16))) unsigned short dbuf[NB*72];   // d(t+1) bf16, cols 7..31 = 0
    __shared__ __attribute__((aligned(16))) unsigned short whis_lds[16*136]; // W_hist bf16, rows 7..15 = 0
    __shared__ float xs[NB*8], msh[NB*8], dsl[NB*8];
    __shared__ float xh_l[NB*8], xc_l[NB*8], gx_l[NB*8];
    __shared__ float bhist_l[8], tdx_l[8], btdx_l[8];
    __shared__ float impbuf[NB*16*7];       // 16-step imputation buffer (fp32)
    __shared__ float red[8];

    const int tid  = threadIdx.x;
    const int b0   = blockIdx.x * NB;
    const int lane = tid & 63;
    const int w    = tid >> 6;      // wave 0..7
    const int quad = lane >> 4;
    const int l15  = lane & 15;

    // ---- one-time LDS init ----
    for (int i = tid; i < NB*168; i += NTHR) hbuf[i] = 0;
    for (int i = tid; i < NB*72;  i += NTHR) dbuf[i] = 0;
    for (int i = tid; i < 16*136; i += NTHR) {
        int r = i / 136, c = i - r*136;
        whis_lds[i] = (r < 7 && c < 128) ? f2bf(W_hist[r*H_ + c]) : 0;
    }
    if (tid < 8) {
        bhist_l[tid] = (tid < 7) ? b_hist[tid] : 0.f;
        tdx_l[tid]   = (tid < 7) ? W_td_x[tid*D_ + tid] : 0.f;
        btdx_l[tid]  = (tid < 7) ? b_td_x[tid] : 0.f;
    }

    // ---- persistent weight fragments (per lane) ----
    short8 whhf[4][4];   // [gate c][kstep]  A[j=l15 of tile][k=quad*8+e]
    short8 winf[4];      // input kstep (k_ext 0..13 = W_ih, rest 0)
    short8 wtdf;         // W_td_h frag for gamma_h MFMA (j = w*16+l15, k<7)
    float  biasg_r[4][4];
    float  btdh_r[4];
    {
        union UU { short8 v; unsigned short u[8]; } fr;
        #pragma unroll
        for (int c = 0; c < 4; ++c) {
            const int j = (c*8 + w)*16 + l15;
            #pragma unroll
            for (int s = 0; s < 4; ++s) {
                const float* p = W_hh + j*H_ + s*32 + quad*8;
                #pragma unroll
                for (int e = 0; e < 8; ++e) fr.u[e] = f2bf(p[e]);
                whhf[c][s] = fr.v;
            }
            #pragma unroll
            for (int e = 0; e < 8; ++e) {
                int k = quad*8 + e;
                fr.u[e] = (k < 14) ? f2bf(W_ih[j*14 + k]) : (unsigned short)0;
            }
            winf[c] = fr.v;
            #pragma unroll
            for (int r = 0; r < 4; ++r) {
                int jj = (c*8 + w)*16 + quad*4 + r;
                biasg_r[c][r] = b_ih[jj] + b_hh[jj];
            }
        }
        #pragma unroll
        for (int e = 0; e < 8; ++e) {
            int k = quad*8 + e;
            fr.u[e] = (k < 7) ? f2bf(W_td_h[(w*16 + l15)*D_ + k]) : (unsigned short)0;
        }
        wtdf = fr.v;
        #pragma unroll
        for (int r = 0; r < 4; ++r) btdh_r[r] = b_td_h[w*16 + quad*4 + r];
    }

    // ---- A3 per-thread state ----
    const bool ldr = (tid < NB*D_);
    const int  lb  = tid / D_, li = tid - (tid/D_)*D_;
    float wfr[7], wcr[14], bfr = 0.f, bcr = 0.f;
    if (ldr) {
        #pragma unroll
        for (int k = 0; k < 7; ++k)  wfr[k] = (k == li) ? 0.f : W_feat[li*D_ + k];
        #pragma unroll
        for (int k = 0; k < 14; ++k) wcr[k] = W_comb[li*14 + k];
        bfr = b_feat[li];  bcr = b_comb[li];
    }

    float c_st[2][4] = {{0,0,0,0},{0,0,0,0}};
    float lacc = 0.f;

    // input prefetch (regs hold step-t data at loop top)
    const long gbase = (long)(b0 + lb)*TD_ + li;
    float rx = 0.f, rm = 0.f, rd = 0.f;
    if (ldr) { rx = values[gbase]; rm = masks[gbase]; rd = deltas[gbase]; }

    const float* msums = ws + WS_MINV;

    for (int t = 0; t < T_; ++t) {
        if (ldr) { xs[lb*8+li] = rx; msh[lb*8+li] = rm; dsl[lb*8+li] = rd; }
        __syncthreads();                       // [S] stage + prev h-writes visible
        if (ldr) {
            if (t + 1 < T_) {
                const long g = gbase + (long)(t+1)*D_;
                rx = values[g]; rm = masks[g]; rd = deltas[g];
            }
            dbuf[lb*72 + li] = f2bf(rd);       // d(t+1) (stale at t=T-1, unused)
        }

        // ---- B1: gate h-part (+ x_h on wave 7). h in hbuf is ALREADY decayed ----
        floatx4 acc[4][2];
        #pragma unroll
        for (int c = 0; c < 4; ++c)
            #pragma unroll
            for (int nt = 0; nt < 2; ++nt) {
                floatx4 a = { biasg_r[c][0], biasg_r[c][1], biasg_r[c][2], biasg_r[c][3] };
                acc[c][nt] = a;
            }
        floatx4 xh0 = {0,0,0,0}, xh1 = {0,0,0,0};
        #pragma unroll
        for (int s = 0; s < 4; ++s) {
            short8 hb0 = *(const short8*)&hbuf[l15*168       + s*32 + quad*8];
            short8 hb1 = *(const short8*)&hbuf[(16+l15)*168  + s*32 + quad*8];
            #pragma unroll
            for (int c = 0; c < 4; ++c) {
                acc[c][0] = MFMA16(whhf[c][s], hb0, acc[c][0]);
                acc[c][1] = MFMA16(whhf[c][s], hb1, acc[c][1]);
            }
            if (w == 7) {
                short8 wh = *(const short8*)&whis_lds[l15*136 + s*32 + quad*8];
                xh0 = MFMA16(wh, hb0, xh0);
                xh1 = MFMA16(wh, hb1, xh1);
            }
        }
        // wave 7: finish x_h, compute x_c / gamma_x, publish to LDS
        if (w == 7 && quad < 2) {
            #pragma unroll
            for (int nt = 0; nt < 2; ++nt) {
                const int b = nt*16 + l15;
                floatx4 xv = nt ? xh1 : xh0;
                #pragma unroll
                for (int r = 0; r < 4; ++r) {
                    const int i = quad*4 + r;
                    if (i < 7) {
                        float xhv = xv[r] + bhist_l[i];
                        float x = xs[b*8+i], m = msh[b*8+i], d = dsl[b*8+i];
                        xh_l[b*8+i] = xhv;
                        xc_l[b*8+i] = m*x + (1.f-m)*xhv;
                        gx_l[b*8+i] = __expf(-fmaxf(fmaf(d, tdx_l[i], btdx_l[i]), 0.f));
                    }
                }
            }
        }
        __syncthreads();                       // [B] x_h/x_c/gamma_x + dbuf ready

        // ---- fused gamma_h(t+1) via MFMA on d(t+1): hoisted here so it
        //      overlaps the 224-thread A3 phase (dbuf written pre-[B]) ----
        floatx4 g0 = {0,0,0,0}, g1 = {0,0,0,0};
        const bool dec = (t + 1 < T_);
        if (dec) {
            short8 df0 = *(const short8*)&dbuf[l15*72      + quad*8];
            short8 df1 = *(const short8*)&dbuf[(16+l15)*72 + quad*8];
            floatx4 z = {0,0,0,0};
            g0 = MFMA16(wtdf, df0, z);
            g1 = MFMA16(wtdf, df1, z);
        }

        // ---- A3: z_h, alpha, c_h, c_c, imputation, loss; write ext cols ----
        if (ldr) {
            const int b = lb, i = li;
            const float invt = rcp_(msums[t] + 1e-5f);
            const float x = xs[b*8+i], m = msh[b*8+i];
            float zh = bfr;
            #pragma unroll
            for (int k = 0; k < 7; ++k) zh = fmaf(wfr[k], xc_l[b*8+k], zh);
            float al = bcr;
            #pragma unroll
            for (int k = 0; k < 7; ++k) al = fmaf(wcr[k],   gx_l[b*8+k], al);
            #pragma unroll
            for (int k = 0; k < 7; ++k) al = fmaf(wcr[7+k], msh[b*8+k], al);
            const float xhv = xh_l[b*8+i];
            const float ch  = al*zh + (1.f-al)*xhv;
            const float cc  = m*x + (1.f-m)*ch;
            impbuf[(b*16 + (t & 15))*7 + i] = cc;
            hbuf[b*168 + 128 + i] = f2bf(cc);
            hbuf[b*168 + 135 + i] = f2bf(m);
            lacc = fmaf((fabsf(x-xhv) + fabsf(x-zh) + fabsf(x-ch)) * m, invt, lacc);
        }
        __syncthreads();                       // [C] c_c/m ext ready

        // ---- B2: input part ----
        {
            short8 ib0 = *(const short8*)&hbuf[l15*168      + 128 + quad*8];
            short8 ib1 = *(const short8*)&hbuf[(16+l15)*168 + 128 + quad*8];
            #pragma unroll
            for (int c = 0; c < 4; ++c) {
                acc[c][0] = MFMA16(winf[c], ib0, acc[c][0]);
                acc[c][1] = MFMA16(winf[c], ib1, acc[c][1]);
            }
        }
        // ---- LSTM update; write h (pre-decayed for next step) as b64 ----
        #pragma unroll
        for (int nt = 0; nt < 2; ++nt) {
            const int b = nt*16 + l15;
            floatx4 gg = nt ? g1 : g0;
            float hnv[4];
            #pragma unroll
            for (int r = 0; r < 4; ++r) {
                float ig = acc[0][nt][r], fg = acc[1][nt][r];
                float gv = acc[2][nt][r], og = acc[3][nt][r];
                float cn = sigm(fg)*c_st[nt][r] + sigm(ig)*tanh_(gv);
                c_st[nt][r] = cn;
                float hn = sigm(og)*tanh_(cn);
                if (dec) hn *= __expf(-fmaxf(gg[r] + btdh_r[r], 0.f));
                hnv[r] = hn;
            }
            uint2 pk;
            pk.x = (unsigned)f2bf(hnv[0]) | ((unsigned)f2bf(hnv[1]) << 16);
            pk.y = (unsigned)f2bf(hnv[2]) | ((unsigned)f2bf(hnv[3]) << 16);
            *(uint2*)&hbuf[b*168 + w*16 + quad*4] = pk;
        }

        // ---- imputation flush (contiguous 28B runs, 16 steps at a time) ----
        if ((t & 15) == 15 || t == T_ - 1) {
            const int t0 = t & ~15;
            const int b  = tid >> 4, c16 = tid & 15;
            if (t0 + c16 <= t) {
                float* gp = out + (size_t)OUT_IMP + (size_t)(b0+b)*TD_ + (size_t)(t0+c16)*D_;
                const float* lp = &impbuf[(b*16 + c16)*7];
                #pragma unroll
                for (int e = 0; e < 7; ++e) gp[e] = lp[e];
            }
        }
    }
    __syncthreads();

    // ---- x_loss partial reduction ----
    for (int off = 32; off > 0; off >>= 1) lacc += __shfl_down(lacc, off, 64);
    if ((tid & 63) == 0) red[tid >> 6] = lacc;
    __syncthreads();
    if (tid == 0) {
        float s = 0.f;
        #pragma unroll
        for (int q = 0; q < 8; ++q) s += red[q];
        atomicAdd(&ws[WS_ACC], s);
    }
    // ---- final h -> workspace (fp32) ----
    for (int i = tid; i < NB*H_; i += NTHR) {
        int b = i >> 7, j = i & 127;
        ws[WS_HFIN + (size_t)(b0+b)*H_ + j] = bf2f(hbuf[b*168 + j]);
    }
}

// ================= classification head =================
__global__ __launch_bounds__(128) void rits_head(
    const float* __restrict__ probs, const float* __restrict__ ancillary, const int* __restrict__ labels,
    const float* __restrict__ W_anc, const float* __restrict__ b_anc,
    const float* __restrict__ b_cat,
    const float* __restrict__ W_out, const float* __restrict__ b_out,
    float* __restrict__ ws, float* __restrict__ out)
{
    __shared__ float hb[MB*H_];
    __shared__ float ancl[MB*52];
    __shared__ float hc[MB*H_];
    __shared__ float lg[MB*32];
    __shared__ float smx[MB], sinv[MB], ysum[MB];
    __shared__ float sq[MB*32];
    const int tid = threadIdx.x;
    const int bb0 = blockIdx.x * MB;

    for (int i = tid; i < MB*H_; i += 128) hb[i] = ws[WS_HFIN + (size_t)bb0*H_ + i];
    for (int i = tid; i < MB*E_; i += 128) {
        int b = i / E_, e = i - b*E_;
        float s = b_anc[e];
        #pragma unroll
        for (int a = 0; a < A_; ++a) s = fmaf(ancillary[(bb0+b)*A_ + a], W_anc[e*A_ + a], s);
        ancl[b*52+e] = fmaxf(s, 0.f);
    }
    __syncthreads();
    {
        const int j = tid;
        float s[MB];
        #pragma unroll
        for (int b = 0; b < MB; ++b) s[b] = b_cat[j];
        const float* wc = ws + WS_WCATT;
        for (int k = 0; k < H_; ++k) {
            float wv = wc[k*H_ + j];
            #pragma unroll
            for (int b = 0; b < MB; ++b) s[b] = fmaf(hb[b*H_+k], wv, s[b]);
        }
        for (int k = 0; k < E_; ++k) {
            float wv = wc[(H_+k)*H_ + j];
            #pragma unroll
            for (int b = 0; b < MB; ++b) s[b] = fmaf(ancl[b*52+k], wv, s[b]);
        }
        #pragma unroll
        for (int b = 0; b < MB; ++b) hc[b*H_+j] = fmaxf(s[b], 0.f);
    }
    __syncthreads();
    for (int i = tid; i < MB*O_; i += 128) {
        int b = i / O_, o = i - b*O_;
        float s = b_out[o];
        for (int k = 0; k < H_; ++k) s = fmaf(hc[b*H_+k], W_out[o*H_+k], s);
        lg[b*32+o] = s;
    }
    __syncthreads();
    if (tid < MB) {
        float mx = -1e30f;
        for (int o = 0; o < O_; ++o) mx = fmaxf(mx, lg[tid*32+o]);
        float se = 0.f;
        for (int o = 0; o < O_; ++o) se += __expf(lg[tid*32+o] - mx);
        smx[tid] = mx; sinv[tid] = 1.f / se;
    }
    __syncthreads();
    for (int i = tid; i < MB*O_; i += 128) {
        int b = i / O_, o = i - b*O_;
        float y = __expf(lg[b*32+o] - smx[b]) * sinv[b];
        out[OUT_YH + (size_t)(bb0+b)*O_ + o] = y;
        float d = y - probs[(size_t)(bb0+b)*O_ + o];
        sq[b*32+o] = d*d;
    }
    __syncthreads();
    if (tid < MB) {
        float s = 0.f;
        for (int o = 0; o < O_; ++o) s += sq[tid*32+o];
        ysum[tid] = s;
        out[OUT_LAB + bb0 + tid] = (float)labels[bb0 + tid];
    }
    __syncthreads();
    if (tid == 0) {
        float s = 0.f;
        #pragma unroll
        for (int b = 0; b < MB; ++b) s += ysum[b];
        atomicAdd(&ws[WS_ACC+1], s);
    }
}

// ================= finalize scalars =================
__global__ void rits_fin(const float* __restrict__ ws, float* __restrict__ out)
{
    if (blockIdx.x == 0 && threadIdx.x == 0) {
        float xl = ws[WS_ACC] * 0.3f;
        float yl = ws[WS_ACC+1] * (1.0f / (8192.0f + 1e-5f));
        out[0] = xl; out[1] = yl; out[2] = xl + yl;
    }
}

extern "C" void kernel_launch(void* const* d_in, const int* in_sizes, int n_in,
                              void* d_out, int out_size, void* d_ws, size_t ws_size,
                              hipStream_t stream)
{
    const float* values = (const float*)d_in[0];
    const float* masks  = (const float*)d_in[1];
    const float* deltas = (const float*)d_in[2];
    const float* probs  = (const float*)d_in[3];
    const float* ancil  = (const float*)d_in[4];
    const int*   labels = (const int*)  d_in[5];
    const float* W_td_h = (const float*)d_in[6];
    const float* b_td_h = (const float*)d_in[7];
    const float* W_td_x = (const float*)d_in[8];
    const float* b_td_x = (const float*)d_in[9];
    const float* W_hist = (const float*)d_in[10];
    const float* b_hist = (const float*)d_in[11];
    const float* W_feat = (const float*)d_in[12];
    const float* b_feat = (const float*)d_in[13];
    const float* W_comb = (const float*)d_in[14];
    const float* b_comb = (const float*)d_in[15];
    const float* W_ih   = (const float*)d_in[16];
    const float* W_hh   = (const float*)d_in[17];
    const float* b_ih   = (const float*)d_in[18];
    const float* b_hh   = (const float*)d_in[19];
    const float* W_anc  = (const float*)d_in[20];
    const float* b_anc  = (const float*)d_in[21];
    const float* W_cat  = (const float*)d_in[22];
    const float* b_cat  = (const float*)d_in[23];
    const float* W_out  = (const float*)d_in[24];
    const float* b_out  = (const float*)d_in[25];
    float* ws  = (float*)d_ws;
    float* out = (float*)d_out;

    hipLaunchKernelGGL(rits_prep, dim3((H_*178 + 255)/256), dim3(256), 0, stream, W_cat, ws);
    hipLaunchKernelGGL(rits_msum, dim3(7*MS_BG), dim3(256), 0, stream, masks, ws);
    hipLaunchKernelGGL(rits_main, dim3(B_/NB), dim3(NTHR), 0, stream,
                       values, masks, deltas, W_td_h, b_td_h, W_td_x, b_td_x,
                       W_hist, b_hist, W_feat, b_feat, W_comb, b_comb,
                       W_ih, W_hh, b_ih, b_hh, ws, out);
    hipLaunchKernelGGL(rits_head, dim3(B_/MB), dim3(128), 0, stream,
                       probs, ancil, labels, W_anc, b_anc, b_cat, W_out, b_out, ws, out);
    hipLaunchKernelGGL(rits_fin, dim3(1), dim3(1), 0, stream, ws, out);
}

// Round 5
// 925.560 us; speedup vs baseline: 3.8095x; 1.0089x over previous
//
#include <hip/hip_runtime.h>
#include <math.h>

// ---------------- problem constants ----------------
#define B_ 8192
#define T_ 223
#define D_ 7
#define H_ 128
#define E_ 50
#define O_ 29
#define A_ 9
#define TD_ (T_*D_)     // 1561
#define NB 32           // batch rows per block (main kernel) -> grid 256 = 1 block/CU
#define NTHR 512
#define MB 8            // batch rows per block (head kernel)
#define MS_BG 128       // msum batch groups

// ---------------- workspace layout (float offsets) ----------------
#define WS_MINV  0                            // raw msum_t sums, T floats
#define WS_ACC   (WS_MINV + T_)               // [0]=x_loss raw sum, [1]=y_loss raw sum
#define WS_WCATT (WS_ACC + 2)                 // [178][128] transposed W_cat
#define WS_HFIN  (WS_WCATT + 178*H_)          // final h, [B][128] fp32

// ---------------- output layout (floats) ----------------
#define OUT_YH  3
#define OUT_IMP (OUT_YH + B_*O_)              // 237571
#define OUT_LAB (OUT_IMP + B_*T_*D_)          // 13025283

typedef __attribute__((ext_vector_type(8))) short short8;   // 8 bf16 = 4 VGPRs
typedef __attribute__((ext_vector_type(4))) float floatx4;
#define MFMA16(Av,Bv,Cv) __builtin_amdgcn_mfma_f32_16x16x32_bf16((Av),(Bv),(Cv),0,0,0)

__device__ __forceinline__ unsigned short f2bf(float f) {   // RNE fp32->bf16
    unsigned int u = __builtin_bit_cast(unsigned int, f);
    return (unsigned short)((u + 0x7FFFu + ((u >> 16) & 1u)) >> 16);
}
__device__ __forceinline__ float bf2f(unsigned short s) {
    unsigned int u = ((unsigned int)s) << 16;
    return __builtin_bit_cast(float, u);
}
__device__ __forceinline__ float rcp_(float x)  { return __builtin_amdgcn_rcpf(x); }
__device__ __forceinline__ float sigm(float x)  { return rcp_(1.f + __expf(-x)); }
__device__ __forceinline__ float tanh_(float x) { return 1.f - 2.f*rcp_(1.f + __expf(2.f*x)); }

// ================= prep: W_cat transpose + zero accumulators =================
__global__ void rits_prep(const float* __restrict__ W_cat, float* __restrict__ ws)
{
    int idx = blockIdx.x * 256 + threadIdx.x;
    if (idx < H_*178) {                      // W_cat [128][178] -> [178][128]
        int j = idx / 178, k = idx - j*178;
        ws[WS_WCATT + k*H_ + j] = W_cat[idx];
    }
    if (idx < T_) ws[WS_MINV + idx] = 0.f;
    if (idx < 2) ws[WS_ACC + idx] = 0.f;
}

// ================= per-step mask sums (coalesced, atomic partials) =================
__global__ void rits_msum(const float* __restrict__ masks, float* __restrict__ ws)
{
    const int tc = blockIdx.x % 7;           // t-chunk of 32 steps
    const int bg = blockIdx.x / 7;           // batch group
    const int t0 = tc * 32;
    const int nt = (t0 + 32 <= T_) ? 32 : (T_ - t0);
    const int ncol = nt * D_;                // 224 or 217
    const int tid = threadIdx.x;
    __shared__ float sums[224];
    float s = 0.f;
    if (tid < ncol) {
        const int bpg = B_ / MS_BG;          // 64
        const float* p = masks + (size_t)bg * bpg * TD_ + (size_t)t0 * D_ + tid;
        #pragma unroll 4
        for (int b = 0; b < bpg; ++b) s += p[(size_t)b * TD_];
    }
    if (tid < 224) sums[tid] = (tid < ncol) ? s : 0.f;
    __syncthreads();
    if (tid < 32) {
        float r = 0.f;
        #pragma unroll
        for (int q = 0; q < 7; ++q) r += sums[tid*7 + q];
        if (t0 + tid < T_) atomicAdd(&ws[WS_MINV + t0 + tid], r);
    }
}

// ================= main scan kernel (MFMA) =================
// Balanced 3-interval structure (1 block/CU, all weight frags in regs):
//  I1 [S]->[B]: gate-h MFMAs all waves; wave7 adds x_h MFMAs + raw float2
//               publish (tail = 8 MFMA + 4 writes; exp/x_c moved out).
//  I2 [B]->[C]: m-part+gate-bias MFMA + decay MFMA (bbuf: m,1,d(t+1),1)
//               on ALL waves, overlapping A3 (224 thr, conflict-free
//               odd-stride scalar reads, builds x_c from x,m,x_h itself).
//  I3 [C]->[S']: c_c-part MFMA + LSTM (biases already in acc) + h-write.
// gamma_x staged at loop-top by owner thread from register rd (1 exp).
__global__ __launch_bounds__(NTHR, 2) void rits_main(
    const float* __restrict__ values, const float* __restrict__ masks, const float* __restrict__ deltas,
    const float* __restrict__ W_td_h, const float* __restrict__ b_td_h,
    const float* __restrict__ W_td_x, const float* __restrict__ b_td_x,
    const float* __restrict__ W_hist, const float* __restrict__ b_hist,
    const float* __restrict__ W_feat, const float* __restrict__ b_feat,
    const float* __restrict__ W_comb, const float* __restrict__ b_comb,
    const float* __restrict__ W_ih, const float* __restrict__ W_hh,
    const float* __restrict__ b_ih, const float* __restrict__ b_hh,
    float* __restrict__ ws, float* __restrict__ out)
{
    // hbuf row (bf16, stride 168): 0..127 h, 128..134 c_c, 135..159 zeros
    __shared__ __attribute__((aligned(16))) unsigned short hbuf[NB*168];
    // bbuf row (bf16, stride 32): 0..6 m(t), 7=1.0, 8..14 d(t+1), 15=1.0, 16..31=0
    __shared__ __attribute__((aligned(16))) unsigned short bbuf[NB*32];
    __shared__ __attribute__((aligned(16))) unsigned short whis_lds[16*136]; // W_hist bf16, rows 7..15 = 0
    __shared__ float xm_l[NB*18];           // (x,m) float2 pairs, stride 18 (conflict-free)
    __shared__ float gx_l[NB*9];            // gamma_x, stride 9
    __shared__ float xh_l[NB*10];           // x_h raw (bias added), stride 10, float2-aligned
    __shared__ float impbuf[NB*16*7];       // 16-step imputation buffer (fp32)
    __shared__ float red[8];

    const int tid  = threadIdx.x;
    const int b0   = blockIdx.x * NB;
    const int lane = tid & 63;
    const int w    = tid >> 6;      // wave 0..7
    const int quad = lane >> 4;
    const int l15  = lane & 15;

    // ---- one-time LDS init ----
    for (int i = tid; i < NB*168; i += NTHR) hbuf[i] = 0;
    for (int i = tid; i < NB*32;  i += NTHR) bbuf[i] = 0;
    for (int i = tid; i < 16*136; i += NTHR) {
        int r = i / 136, c = i - r*136;
        whis_lds[i] = (r < 7 && c < 128) ? f2bf(W_hist[r*H_ + c]) : 0;
    }
    __syncthreads();                 // zeros visible before bias-column pokes
    if (tid < NB) {
        bbuf[tid*32 + 7]  = 0x3F80;  // 1.0 -> gate-bias column
        bbuf[tid*32 + 15] = 0x3F80;  // 1.0 -> decay-bias column
    }

    // ---- persistent weight fragments (per lane) ----
    short8 whhf[4][4];   // [gate c][kstep]  A[j=l15 of tile][k=quad*8+e]
    short8 winf_c[4];    // c_c part: k0..6 = W_ih[:, 0..6], rest 0
    short8 winf_mb[4];   // m part:   k0..6 = W_ih[:, 7..13], k7 = b_ih+b_hh, rest 0
    short8 wtdf;         // decay:    k8..14 = W_td_h, k15 = b_td_h, rest 0
    float  bh_r[4];      // b_hist for wave7 publish
    {
        union UU { short8 v; unsigned short u[8]; } fr;
        #pragma unroll
        for (int c = 0; c < 4; ++c) {
            const int j = (c*8 + w)*16 + l15;
            #pragma unroll
            for (int s = 0; s < 4; ++s) {
                const float* p = W_hh + j*H_ + s*32 + quad*8;
                #pragma unroll
                for (int e = 0; e < 8; ++e) fr.u[e] = f2bf(p[e]);
                whhf[c][s] = fr.v;
            }
            #pragma unroll
            for (int e = 0; e < 8; ++e) {
                int k = quad*8 + e;
                fr.u[e] = (k < 7) ? f2bf(W_ih[j*14 + k]) : (unsigned short)0;
            }
            winf_c[c] = fr.v;
            #pragma unroll
            for (int e = 0; e < 8; ++e) {
                int k = quad*8 + e;
                float v = (k < 7) ? W_ih[j*14 + 7 + k]
                        : ((k == 7) ? (b_ih[j] + b_hh[j]) : 0.f);
                fr.u[e] = f2bf(v);
            }
            winf_mb[c] = fr.v;
        }
        const int j2 = w*16 + l15;
        #pragma unroll
        for (int e = 0; e < 8; ++e) {
            int k = quad*8 + e;
            float v = (k >= 8 && k < 15) ? W_td_h[j2*D_ + (k - 8)]
                    : ((k == 15) ? b_td_h[j2] : 0.f);
            fr.u[e] = f2bf(v);
        }
        wtdf = fr.v;
        #pragma unroll
        for (int r = 0; r < 4; ++r) {
            int f = quad*4 + r;
            bh_r[r] = (quad < 2 && f < 7) ? b_hist[f] : 0.f;
        }
    }

    // ---- A3 per-thread state ----
    const bool ldr = (tid < NB*D_);
    const int  lb  = tid / D_, li = tid - (tid/D_)*D_;
    float wfr[7], wcr[14], bfr = 0.f, bcr = 0.f, tdx_own = 0.f, btdx_own = 0.f;
    if (ldr) {
        #pragma unroll
        for (int k = 0; k < 7; ++k)  wfr[k] = (k == li) ? 0.f : W_feat[li*D_ + k];
        #pragma unroll
        for (int k = 0; k < 14; ++k) wcr[k] = W_comb[li*14 + k];
        bfr = b_feat[li];  bcr = b_comb[li];
        tdx_own = W_td_x[li*D_ + li];  btdx_own = b_td_x[li];
    }

    float c_st[2][4] = {{0,0,0,0},{0,0,0,0}};
    float lacc = 0.f;

    // input prefetch (regs hold step-t data at loop top)
    const long gbase = (long)(b0 + lb)*TD_ + li;
    float rx = 0.f, rm = 0.f, rd = 0.f;
    if (ldr) { rx = values[gbase]; rm = masks[gbase]; rd = deltas[gbase]; }

    const float* msums = ws + WS_MINV;

    for (int t = 0; t < T_; ++t) {
        // ---- stage (owner-computed gamma_x; m into bbuf) ----
        if (ldr) {
            float2 s2 = { rx, rm };
            *(float2*)&xm_l[lb*18 + 2*li] = s2;
            gx_l[lb*9 + li] = __expf(-fmaxf(fmaf(rd, tdx_own, btdx_own), 0.f));
            bbuf[lb*32 + li] = f2bf(rm);
        }
        __syncthreads();                       // [S] stage + prev h-writes visible
        if (ldr && t + 1 < T_) {
            const long g = gbase + (long)(t+1)*D_;
            rx = values[g]; rm = masks[g]; rd = deltas[g];
            bbuf[lb*32 + 8 + li] = f2bf(rd);   // d(t+1) for fused decay
        }

        // ---- I1: gate h-part (+ x_h on wave 7). h in hbuf is ALREADY decayed ----
        floatx4 acc[4][2];
        #pragma unroll
        for (int c = 0; c < 4; ++c)
            #pragma unroll
            for (int nt = 0; nt < 2; ++nt) { floatx4 z = {0,0,0,0}; acc[c][nt] = z; }
        floatx4 xh0 = {0,0,0,0}, xh1 = {0,0,0,0};
        #pragma unroll
        for (int s = 0; s < 4; ++s) {
            short8 hb0 = *(const short8*)&hbuf[l15*168       + s*32 + quad*8];
            short8 hb1 = *(const short8*)&hbuf[(16+l15)*168  + s*32 + quad*8];
            #pragma unroll
            for (int c = 0; c < 4; ++c) {
                acc[c][0] = MFMA16(whhf[c][s], hb0, acc[c][0]);
                acc[c][1] = MFMA16(whhf[c][s], hb1, acc[c][1]);
            }
            if (w == 7) {
                short8 wh = *(const short8*)&whis_lds[l15*136 + s*32 + quad*8];
                xh0 = MFMA16(wh, hb0, xh0);
                xh1 = MFMA16(wh, hb1, xh1);
            }
        }
        // wave 7: publish raw x_h (bias added) as float2 pairs — short tail
        if (w == 7 && quad < 2) {
            #pragma unroll
            for (int nt = 0; nt < 2; ++nt) {
                const int b = nt*16 + l15;
                floatx4 xv = nt ? xh1 : xh0;
                float2 p0 = { xv[0] + bh_r[0], xv[1] + bh_r[1] };
                float2 p1 = { xv[2] + bh_r[2], xv[3] + bh_r[3] };
                *(float2*)&xh_l[b*10 + quad*4]     = p0;
                *(float2*)&xh_l[b*10 + quad*4 + 2] = p1;
            }
        }
        __syncthreads();                       // [B] x_h + bbuf(d) ready

        // ---- I2: m-part + gate-bias + decay MFMAs (all waves, idle pipe) ----
        const bool dec = (t + 1 < T_);
        floatx4 g0 = {0,0,0,0}, g1 = {0,0,0,0};
        {
            short8 bb0 = *(const short8*)&bbuf[l15*32      + quad*8];
            short8 bb1 = *(const short8*)&bbuf[(16+l15)*32 + quad*8];
            #pragma unroll
            for (int c = 0; c < 4; ++c) {
                acc[c][0] = MFMA16(winf_mb[c], bb0, acc[c][0]);
                acc[c][1] = MFMA16(winf_mb[c], bb1, acc[c][1]);
            }
            if (dec) {
                floatx4 z = {0,0,0,0};
                g0 = MFMA16(wtdf, bb0, z);
                g1 = MFMA16(wtdf, bb1, z);
            }
        }

        // ---- A3: z_h, alpha, c_h, c_c, imputation, loss (conflict-free reads) ----
        if (ldr) {
            const int b = lb, i = li;
            const float invt = rcp_(msums[t] + 1e-5f);
            const float x = xm_l[b*18 + 2*i], m = xm_l[b*18 + 2*i + 1];
            const float xhv = xh_l[b*10 + i];
            float zh = bfr, al = bcr;
            #pragma unroll
            for (int k = 0; k < 7; ++k) {
                const float xk  = xm_l[b*18 + 2*k];
                const float mk  = xm_l[b*18 + 2*k + 1];
                const float xhk = xh_l[b*10 + k];
                const float xck = mk*xk + (1.f - mk)*xhk;
                zh = fmaf(wfr[k], xck, zh);
                al = fmaf(wcr[k], gx_l[b*9 + k], al);
                al = fmaf(wcr[7+k], mk, al);
            }
            const float ch = al*zh + (1.f - al)*xhv;
            const float cc = m*x + (1.f - m)*ch;
            impbuf[(b*16 + (t & 15))*7 + i] = cc;
            hbuf[b*168 + 128 + i] = f2bf(cc);
            lacc = fmaf((fabsf(x-xhv) + fabsf(x-zh) + fabsf(x-ch)) * m, invt, lacc);
        }
        __syncthreads();                       // [C] c_c ext ready

        // ---- I3: c_c-part MFMA ----
        {
            short8 ib0 = *(const short8*)&hbuf[l15*168      + 128 + quad*8];
            short8 ib1 = *(const short8*)&hbuf[(16+l15)*168 + 128 + quad*8];
            #pragma unroll
            for (int c = 0; c < 4; ++c) {
                acc[c][0] = MFMA16(winf_c[c], ib0, acc[c][0]);
                acc[c][1] = MFMA16(winf_c[c], ib1, acc[c][1]);
            }
        }
        // ---- LSTM update; write h (pre-decayed for next step) as b64 ----
        #pragma unroll
        for (int nt = 0; nt < 2; ++nt) {
            const int b = nt*16 + l15;
            floatx4 gg = nt ? g1 : g0;
            float hnv[4];
            #pragma unroll
            for (int r = 0; r < 4; ++r) {
                float ig = acc[0][nt][r], fg = acc[1][nt][r];
                float gv = acc[2][nt][r], og = acc[3][nt][r];
                float cn = sigm(fg)*c_st[nt][r] + sigm(ig)*tanh_(gv);
                c_st[nt][r] = cn;
                float hn = sigm(og)*tanh_(cn);
                if (dec) hn *= __expf(-fmaxf(gg[r], 0.f));
                hnv[r] = hn;
            }
            uint2 pk;
            pk.x = (unsigned)f2bf(hnv[0]) | ((unsigned)f2bf(hnv[1]) << 16);
            pk.y = (unsigned)f2bf(hnv[2]) | ((unsigned)f2bf(hnv[3]) << 16);
            *(uint2*)&hbuf[b*168 + w*16 + quad*4] = pk;
        }

        // ---- imputation flush (contiguous 28B runs, 16 steps at a time) ----
        if ((t & 15) == 15 || t == T_ - 1) {
            const int t0 = t & ~15;
            const int b  = tid >> 4, c16 = tid & 15;
            if (t0 + c16 <= t) {
                float* gp = out + (size_t)OUT_IMP + (size_t)(b0+b)*TD_ + (size_t)(t0+c16)*D_;
                const float* lp = &impbuf[(b*16 + c16)*7];
                #pragma unroll
                for (int e = 0; e < 7; ++e) gp[e] = lp[e];
            }
        }
    }
    __syncthreads();

    // ---- x_loss partial reduction ----
    for (int off = 32; off > 0; off >>= 1) lacc += __shfl_down(lacc, off, 64);
    if ((tid & 63) == 0) red[tid >> 6] = lacc;
    __syncthreads();
    if (tid == 0) {
        float s = 0.f;
        #pragma unroll
        for (int q = 0; q < 8; ++q) s += red[q];
        atomicAdd(&ws[WS_ACC], s);
    }
    // ---- final h -> workspace (fp32) ----
    for (int i = tid; i < NB*H_; i += NTHR) {
        int b = i >> 7, j = i & 127;
        ws[WS_HFIN + (size_t)(b0+b)*H_ + j] = bf2f(hbuf[b*168 + j]);
    }
}

// ================= classification head =================
__global__ __launch_bounds__(128) void rits_head(
    const float* __restrict__ probs, const float* __restrict__ ancillary, const int* __restrict__ labels,
    const float* __restrict__ W_anc, const float* __restrict__ b_anc,
    const float* __restrict__ b_cat,
    const float* __restrict__ W_out, const float* __restrict__ b_out,
    float* __restrict__ ws, float* __restrict__ out)
{
    __shared__ float hb[MB*H_];
    __shared__ float ancl[MB*52];
    __shared__ float hc[MB*H_];
    __shared__ float lg[MB*32];
    __shared__ float smx[MB], sinv[MB], ysum[MB];
    __shared__ float sq[MB*32];
    const int tid = threadIdx.x;
    const int bb0 = blockIdx.x * MB;

    for (int i = tid; i < MB*H_; i += 128) hb[i] = ws[WS_HFIN + (size_t)bb0*H_ + i];
    for (int i = tid; i < MB*E_; i += 128) {
        int b = i / E_, e = i - b*E_;
        float s = b_anc[e];
        #pragma unroll
        for (int a = 0; a < A_; ++a) s = fmaf(ancillary[(bb0+b)*A_ + a], W_anc[e*A_ + a], s);
        ancl[b*52+e] = fmaxf(s, 0.f);
    }
    __syncthreads();
    {
        const int j = tid;
        float s[MB];
        #pragma unroll
        for (int b = 0; b < MB; ++b) s[b] = b_cat[j];
        const float* wc = ws + WS_WCATT;
        for (int k = 0; k < H_; ++k) {
            float wv = wc[k*H_ + j];
            #pragma unroll
            for (int b = 0; b < MB; ++b) s[b] = fmaf(hb[b*H_+k], wv, s[b]);
        }
        for (int k = 0; k < E_; ++k) {
            float wv = wc[(H_+k)*H_ + j];
            #pragma unroll
            for (int b = 0; b < MB; ++b) s[b] = fmaf(ancl[b*52+k], wv, s[b]);
        }
        #pragma unroll
        for (int b = 0; b < MB; ++b) hc[b*H_+j] = fmaxf(s[b], 0.f);
    }
    __syncthreads();
    for (int i = tid; i < MB*O_; i += 128) {
        int b = i / O_, o = i - b*O_;
        float s = b_out[o];
        for (int k = 0; k < H_; ++k) s = fmaf(hc[b*H_+k], W_out[o*H_+k], s);
        lg[b*32+o] = s;
    }
    __syncthreads();
    if (tid < MB) {
        float mx = -1e30f;
        for (int o = 0; o < O_; ++o) mx = fmaxf(mx, lg[tid*32+o]);
        float se = 0.f;
        for (int o = 0; o < O_; ++o) se += __expf(lg[tid*32+o] - mx);
        smx[tid] = mx; sinv[tid] = 1.f / se;
    }
    __syncthreads();
    for (int i = tid; i < MB*O_; i += 128) {
        int b = i / O_, o = i - b*O_;
        float y = __expf(lg[b*32+o] - smx[b]) * sinv[b];
        out[OUT_YH + (size_t)(bb0+b)*O_ + o] = y;
        float d = y - probs[(size_t)(bb0+b)*O_ + o];
        sq[b*32+o] = d*d;
    }
    __syncthreads();
    if (tid < MB) {
        float s = 0.f;
        for (int o = 0; o < O_; ++o) s += sq[tid*32+o];
        ysum[tid] = s;
        out[OUT_LAB + bb0 + tid] = (float)labels[bb0 + tid];
    }
    __syncthreads();
    if (tid == 0) {
        float s = 0.f;
        #pragma unroll
        for (int b = 0; b < MB; ++b) s += ysum[b];
        atomicAdd(&ws[WS_ACC+1], s);
    }
}

// ================= finalize scalars =================
__global__ void rits_fin(const float* __restrict__ ws, float* __restrict__ out)
{
    if (blockIdx.x == 0 && threadIdx.x == 0) {
        float xl = ws[WS_ACC] * 0.3f;
        float yl = ws[WS_ACC+1] * (1.0f / (8192.0f + 1e-5f));
        out[0] = xl; out[1] = yl; out[2] = xl + yl;
    }
}

extern "C" void kernel_launch(void* const* d_in, const int* in_sizes, int n_in,
                              void* d_out, int out_size, void* d_ws, size_t ws_size,
                              hipStream_t stream)
{
    const float* values = (const float*)d_in[0];
    const float* masks  = (const float*)d_in[1];
    const float* deltas = (const float*)d_in[2];
    const float* probs  = (const float*)d_in[3];
    const float* ancil  = (const float*)d_in[4];
    const int*   labels = (const int*)  d_in[5];
    const float* W_td_h = (const float*)d_in[6];
    const float* b_td_h = (const float*)d_in[7];
    const float* W_td_x = (const float*)d_in[8];
    const float* b_td_x = (const float*)d_in[9];
    const float* W_hist = (const float*)d_in[10];
    const float* b_hist = (const float*)d_in[11];
    const float* W_feat = (const float*)d_in[12];
    const float* b_feat = (const float*)d_in[13];
    const float* W_comb = (const float*)d_in[14];
    const float* b_comb = (const float*)d_in[15];
    const float* W_ih   = (const float*)d_in[16];
    const float* W_hh   = (const float*)d_in[17];
    const float* b_ih   = (const float*)d_in[18];
    const float* b_hh   = (const float*)d_in[19];
    const float* W_anc  = (const float*)d_in[20];
    const float* b_anc  = (const float*)d_in[21];
    const float* W_cat  = (const float*)d_in[22];
    const float* b_cat  = (const float*)d_in[23];
    const float* W_out  = (const float*)d_in[24];
    const float* b_out  = (const float*)d_in[25];
    float* ws  = (float*)d_ws;
    float* out = (float*)d_out;

    hipLaunchKernelGGL(rits_prep, dim3((H_*178 + 255)/256), dim3(256), 0, stream, W_cat, ws);
    hipLaunchKernelGGL(rits_msum, dim3(7*MS_BG), dim3(256), 0, stream, masks, ws);
    hipLaunchKernelGGL(rits_main, dim3(B_/NB), dim3(NTHR), 0, stream,
                       values, masks, deltas, W_td_h, b_td_h, W_td_x, b_td_x,
                       W_hist, b_hist, W_feat, b_feat, W_comb, b_comb,
                       W_ih, W_hh, b_ih, b_hh, ws, out);
    hipLaunchKernelGGL(rits_head, dim3(B_/MB), dim3(128), 0, stream,
                       probs, ancil, labels, W_anc, b_anc, b_cat, W_out, b_out, ws, out);
    hipLaunchKernelGGL(rits_fin, dim3(1), dim3(1), 0, stream, ws, out);
}